// Round 1
// baseline (811.929 us; speedup 1.0000x reference)
//
#include <hip/hip_runtime.h>
#include <hip/hip_bf16.h>
#include <math.h>

#define H_  12
#define N_  1620
#define D_  64
#define C_  768
#define NS_ 20
#define V_  4
#define P_  400
#define K_  64

// ---------------------------------------------------------------------------
// NT GEMM: C[m][n] = sum_k A[m][k] * B[n][k] + bias[n]
// A: M x Kd row-major, B: N x Kd row-major.
// MODE 0: write C row-major (M x N) into out0.
// MODE 1: QKV scatter: n -> (which, h, d); write into q/k/v [h][N_][D_].
// ---------------------------------------------------------------------------
template<int MODE>
__global__ __launch_bounds__(256)
void gemm_nt(const float* __restrict__ A, const float* __restrict__ B,
             const float* __restrict__ bias, int M, int N, int Kd,
             float* __restrict__ out0, float* __restrict__ out1,
             float* __restrict__ out2)
{
    __shared__ float As[16][64];
    __shared__ float Bs[16][64];
    const int tid = threadIdx.x;
    const int bm = blockIdx.x * 64;
    const int bn = blockIdx.y * 64;
    const int tx = tid & 15, ty = tid >> 4;
    const int lrow = tid >> 2;          // 0..63
    const int lk4  = (tid & 3) << 2;    // 0,4,8,12

    float acc[4][4] = {};

    for (int k0 = 0; k0 < Kd; k0 += 16) {
        int gm = bm + lrow;
        float4 a4 = make_float4(0.f, 0.f, 0.f, 0.f);
        if (gm < M) a4 = *(const float4*)(A + (size_t)gm * Kd + k0 + lk4);
        As[lk4 + 0][lrow] = a4.x; As[lk4 + 1][lrow] = a4.y;
        As[lk4 + 2][lrow] = a4.z; As[lk4 + 3][lrow] = a4.w;

        int gn = bn + lrow;
        float4 b4 = make_float4(0.f, 0.f, 0.f, 0.f);
        if (gn < N) b4 = *(const float4*)(B + (size_t)gn * Kd + k0 + lk4);
        Bs[lk4 + 0][lrow] = b4.x; Bs[lk4 + 1][lrow] = b4.y;
        Bs[lk4 + 2][lrow] = b4.z; Bs[lk4 + 3][lrow] = b4.w;

        __syncthreads();
        #pragma unroll
        for (int kk = 0; kk < 16; kk++) {
            float4 av = *(const float4*)&As[kk][ty << 2];
            float4 bv = *(const float4*)&Bs[kk][tx << 2];
            float a_[4] = {av.x, av.y, av.z, av.w};
            float b_[4] = {bv.x, bv.y, bv.z, bv.w};
            #pragma unroll
            for (int i = 0; i < 4; i++)
                #pragma unroll
                for (int j = 0; j < 4; j++)
                    acc[i][j] = fmaf(a_[i], b_[j], acc[i][j]);
        }
        __syncthreads();
    }

    #pragma unroll
    for (int i = 0; i < 4; i++) {
        int m = bm + (ty << 2) + i;
        if (m >= M) continue;
        #pragma unroll
        for (int j = 0; j < 4; j++) {
            int n = bn + (tx << 2) + j;
            if (n >= N) continue;
            float val = acc[i][j] + bias[n];
            if (MODE == 0) {
                out0[(size_t)m * N + n] = val;
            } else {
                int which = n / C_;
                int r = n - which * C_;
                int h = r >> 6, d = r & 63;
                float* dst = (which == 0) ? out0 : (which == 1) ? out1 : out2;
                dst[((size_t)h * N_ + m) * D_ + d] = val;
            }
        }
    }
}

// ---------------------------------------------------------------------------
// Spatial attention: for each (h, s) with s in [0, NS_): softmax over all
// N_ keys, weighted sum of V. One 256-thread block per row.
// att layout: [n][C_] row-major (n = token), col = h*64 + d.
// ---------------------------------------------------------------------------
__global__ __launch_bounds__(256)
void attn_spatial(const float* __restrict__ q, const float* __restrict__ k,
                  const float* __restrict__ v, float* __restrict__ att)
{
    const int s = blockIdx.x;   // 0..NS_-1
    const int h = blockIdx.y;   // 0..H_-1
    const int tid = threadIdx.x;

    __shared__ float qs[64];
    __shared__ float logits[N_];
    __shared__ float red[256];

    if (tid < 64) qs[tid] = q[((size_t)h * N_ + s) * D_ + tid];
    __syncthreads();

    const float scale = 0.125f;
    for (int n = tid; n < N_; n += 256) {
        const float4* kr = (const float4*)(k + ((size_t)h * N_ + n) * D_);
        float dot = 0.f;
        #pragma unroll
        for (int i = 0; i < 16; i++) {
            float4 kv = kr[i];
            dot = fmaf(kv.x, qs[i * 4 + 0], dot);
            dot = fmaf(kv.y, qs[i * 4 + 1], dot);
            dot = fmaf(kv.z, qs[i * 4 + 2], dot);
            dot = fmaf(kv.w, qs[i * 4 + 3], dot);
        }
        logits[n] = dot * scale;
    }
    __syncthreads();

    // max reduce
    float lmax = -INFINITY;
    for (int n = tid; n < N_; n += 256) lmax = fmaxf(lmax, logits[n]);
    red[tid] = lmax;
    __syncthreads();
    for (int st = 128; st > 0; st >>= 1) {
        if (tid < st) red[tid] = fmaxf(red[tid], red[tid + st]);
        __syncthreads();
    }
    float gmax = red[0];
    __syncthreads();

    // exp + sum
    float lsum = 0.f;
    for (int n = tid; n < N_; n += 256) {
        float e = expf(logits[n] - gmax);
        logits[n] = e;
        lsum += e;
    }
    red[tid] = lsum;
    __syncthreads();
    for (int st = 128; st > 0; st >>= 1) {
        if (tid < st) red[tid] += red[tid + st];
        __syncthreads();
    }
    float inv = 1.0f / red[0];
    __syncthreads();

    // PV: out[d] = sum_n p[n] * v[h][n][d]
    const int d = tid & 63, g = tid >> 6;
    float acc = 0.f;
    for (int n = g; n < N_; n += 4)
        acc = fmaf(logits[n], v[((size_t)h * N_ + n) * D_ + d], acc);
    red[tid] = acc;
    __syncthreads();
    if (g == 0) {
        float r = red[d] + red[64 + d] + red[128 + d] + red[192 + d];
        att[(size_t)s * C_ + h * 64 + d] = r * inv;
    }
}

// ---------------------------------------------------------------------------
// Panoramic attention: for each (h, view, p): 484 keys =
//   [0,20) spatial | [20,420) same view | [420,484) cross_idx gather.
// One 256-thread block per row.
// ---------------------------------------------------------------------------
__global__ __launch_bounds__(256)
void attn_pano(const float* __restrict__ q, const float* __restrict__ k,
               const float* __restrict__ v, const int* __restrict__ cross_idx,
               float* __restrict__ att)
{
    const int p  = blockIdx.x;   // 0..P_-1
    const int vw = blockIdx.y;   // 0..V_-1
    const int h  = blockIdx.z;   // 0..H_-1
    const int tid = threadIdx.x;
    const int NK = NS_ + P_ + K_;   // 484

    __shared__ float qs[64];
    __shared__ float probs[NS_ + P_ + K_];
    __shared__ int   nidx[NS_ + P_ + K_];
    __shared__ float red[256];

    const int qn = NS_ + vw * P_ + p;
    if (tid < 64) qs[tid] = q[((size_t)h * N_ + qn) * D_ + tid];

    for (int j = tid; j < NK; j += 256) {
        int n;
        if (j < NS_)            n = j;
        else if (j < NS_ + P_)  n = NS_ + vw * P_ + (j - NS_);
        else                    n = cross_idx[((size_t)vw * P_ + p) * K_ + (j - NS_ - P_)];
        nidx[j] = n;
    }
    __syncthreads();

    const float scale = 0.125f;
    for (int j = tid; j < NK; j += 256) {
        const float4* kr = (const float4*)(k + ((size_t)h * N_ + nidx[j]) * D_);
        float dot = 0.f;
        #pragma unroll
        for (int i = 0; i < 16; i++) {
            float4 kv = kr[i];
            dot = fmaf(kv.x, qs[i * 4 + 0], dot);
            dot = fmaf(kv.y, qs[i * 4 + 1], dot);
            dot = fmaf(kv.z, qs[i * 4 + 2], dot);
            dot = fmaf(kv.w, qs[i * 4 + 3], dot);
        }
        probs[j] = dot * scale;
    }
    __syncthreads();

    float lmax = -INFINITY;
    for (int j = tid; j < NK; j += 256) lmax = fmaxf(lmax, probs[j]);
    red[tid] = lmax;
    __syncthreads();
    for (int st = 128; st > 0; st >>= 1) {
        if (tid < st) red[tid] = fmaxf(red[tid], red[tid + st]);
        __syncthreads();
    }
    float gmax = red[0];
    __syncthreads();

    float lsum = 0.f;
    for (int j = tid; j < NK; j += 256) {
        float e = expf(probs[j] - gmax);
        probs[j] = e;
        lsum += e;
    }
    red[tid] = lsum;
    __syncthreads();
    for (int st = 128; st > 0; st >>= 1) {
        if (tid < st) red[tid] += red[tid + st];
        __syncthreads();
    }
    float inv = 1.0f / red[0];
    __syncthreads();

    const int d = tid & 63, g = tid >> 6;
    float acc = 0.f;
    for (int j = g; j < NK; j += 4)
        acc = fmaf(probs[j], v[((size_t)h * N_ + nidx[j]) * D_ + d], acc);
    red[tid] = acc;
    __syncthreads();
    if (g == 0) {
        float r = red[d] + red[64 + d] + red[128 + d] + red[192 + d];
        att[(size_t)qn * C_ + h * 64 + d] = r * inv;
    }
}

// ---------------------------------------------------------------------------
extern "C" void kernel_launch(void* const* d_in, const int* in_sizes, int n_in,
                              void* d_out, int out_size, void* d_ws, size_t ws_size,
                              hipStream_t stream)
{
    const float* x       = (const float*)d_in[0];
    const float* qkv_w   = (const float*)d_in[1];
    const float* qkv_b   = (const float*)d_in[2];
    const float* proj_w  = (const float*)d_in[3];
    const float* proj_b  = (const float*)d_in[4];
    const int*   cross   = (const int*)d_in[5];
    float* out = (float*)d_out;

    float* ws = (float*)d_ws;
    const size_t per = (size_t)H_ * N_ * D_;   // 1,244,160 floats
    float* q   = ws;
    float* k   = q + per;
    float* v   = k + per;
    float* att = v + per;                      // N_ x C_ = 1,244,160 floats

    // 1) QKV projection, scatter into q/k/v [h][n][d]
    dim3 g1((N_ + 63) / 64, (3 * C_) / 64);    // 26 x 36
    gemm_nt<1><<<g1, 256, 0, stream>>>(x, qkv_w, qkv_b, N_, 3 * C_, C_, q, k, v);

    // 2) spatial attention rows (n < NS_)
    attn_spatial<<<dim3(NS_, H_), 256, 0, stream>>>(q, k, v, att);

    // 3) panoramic attention rows
    attn_pano<<<dim3(P_, V_, H_), 256, 0, stream>>>(q, k, v, cross, att);

    // 4) output projection
    dim3 g2((N_ + 63) / 64, C_ / 64);          // 26 x 12
    gemm_nt<0><<<g2, 256, 0, stream>>>(att, proj_w, proj_b, N_, C_, C_, out, nullptr, nullptr);
}

// Round 3
// 381.611 us; speedup vs baseline: 2.1276x; 2.1276x over previous
//
#include <hip/hip_runtime.h>
#include <hip/hip_bf16.h>
#include <math.h>

#define H_  12
#define N_  1620
#define D_  64
#define C_  768
#define NS_ 20
#define V_  4
#define P_  400

#define TP    32     // q rows per pano block
#define NTILE 13     // ceil(400/32)
#define NCH   7      // shared chunks of 64 cols (448, 420 valid)
#define NBW   96     // neighbor window cols (95 used + 1 pad)

// ---------------------------------------------------------------------------
// NT GEMM: C[m][n] = sum_k A[m][k] * B[n][k] + bias[n]
// MODE 0: write C row-major. MODE 1: QKV scatter into q/k/v [h][N_][D_].
// ---------------------------------------------------------------------------
template<int MODE>
__global__ __launch_bounds__(256)
void gemm_nt(const float* __restrict__ A, const float* __restrict__ B,
             const float* __restrict__ bias, int M, int N, int Kd,
             float* __restrict__ out0, float* __restrict__ out1,
             float* __restrict__ out2)
{
    __shared__ float As[16][64];
    __shared__ float Bs[16][64];
    const int tid = threadIdx.x;
    const int bm = blockIdx.x * 64;
    const int bn = blockIdx.y * 64;
    const int tx = tid & 15, ty = tid >> 4;
    const int lrow = tid >> 2;
    const int lk4  = (tid & 3) << 2;

    float acc[4][4] = {};

    for (int k0 = 0; k0 < Kd; k0 += 16) {
        int gm = bm + lrow;
        float4 a4 = make_float4(0.f, 0.f, 0.f, 0.f);
        if (gm < M) a4 = *(const float4*)(A + (size_t)gm * Kd + k0 + lk4);
        As[lk4 + 0][lrow] = a4.x; As[lk4 + 1][lrow] = a4.y;
        As[lk4 + 2][lrow] = a4.z; As[lk4 + 3][lrow] = a4.w;

        int gn = bn + lrow;
        float4 b4 = make_float4(0.f, 0.f, 0.f, 0.f);
        if (gn < N) b4 = *(const float4*)(B + (size_t)gn * Kd + k0 + lk4);
        Bs[lk4 + 0][lrow] = b4.x; Bs[lk4 + 1][lrow] = b4.y;
        Bs[lk4 + 2][lrow] = b4.z; Bs[lk4 + 3][lrow] = b4.w;

        __syncthreads();
        #pragma unroll
        for (int kk = 0; kk < 16; kk++) {
            float4 av = *(const float4*)&As[kk][ty << 2];
            float4 bv = *(const float4*)&Bs[kk][tx << 2];
            float a_[4] = {av.x, av.y, av.z, av.w};
            float b_[4] = {bv.x, bv.y, bv.z, bv.w};
            #pragma unroll
            for (int i = 0; i < 4; i++)
                #pragma unroll
                for (int j = 0; j < 4; j++)
                    acc[i][j] = fmaf(a_[i], b_[j], acc[i][j]);
        }
        __syncthreads();
    }

    #pragma unroll
    for (int i = 0; i < 4; i++) {
        int m = bm + (ty << 2) + i;
        if (m >= M) continue;
        #pragma unroll
        for (int j = 0; j < 4; j++) {
            int n = bn + (tx << 2) + j;
            if (n >= N) continue;
            float val = acc[i][j] + bias[n];
            if (MODE == 0) {
                out0[(size_t)m * N + n] = val;
            } else {
                int which = n / C_;
                int r = n - which * C_;
                int h = r >> 6, d = r & 63;
                float* dst = (which == 0) ? out0 : (which == 1) ? out1 : out2;
                dst[((size_t)h * N_ + m) * D_ + d] = val;
            }
        }
    }
}

// ---------------------------------------------------------------------------
// Spatial attention (20 rows x 1620 keys), one block per (s, h).
// ---------------------------------------------------------------------------
__global__ __launch_bounds__(256)
void attn_spatial(const float* __restrict__ q, const float* __restrict__ k,
                  const float* __restrict__ v, float* __restrict__ att)
{
    const int s = blockIdx.x;
    const int h = blockIdx.y;
    const int tid = threadIdx.x;

    __shared__ float qs[64];
    __shared__ float logits[N_];
    __shared__ float red[256];

    if (tid < 64) qs[tid] = q[((size_t)h * N_ + s) * D_ + tid];
    __syncthreads();

    const float scale = 0.125f;
    for (int n = tid; n < N_; n += 256) {
        const float4* kr = (const float4*)(k + ((size_t)h * N_ + n) * D_);
        float dot = 0.f;
        #pragma unroll
        for (int i = 0; i < 16; i++) {
            float4 kv = kr[i];
            dot = fmaf(kv.x, qs[i * 4 + 0], dot);
            dot = fmaf(kv.y, qs[i * 4 + 1], dot);
            dot = fmaf(kv.z, qs[i * 4 + 2], dot);
            dot = fmaf(kv.w, qs[i * 4 + 3], dot);
        }
        logits[n] = dot * scale;
    }
    __syncthreads();

    float lmax = -INFINITY;
    for (int n = tid; n < N_; n += 256) lmax = fmaxf(lmax, logits[n]);
    red[tid] = lmax;
    __syncthreads();
    for (int st = 128; st > 0; st >>= 1) {
        if (tid < st) red[tid] = fmaxf(red[tid], red[tid + st]);
        __syncthreads();
    }
    float gmax = red[0];
    __syncthreads();

    float lsum = 0.f;
    for (int n = tid; n < N_; n += 256) {
        float e = __expf(logits[n] - gmax);
        logits[n] = e;
        lsum += e;
    }
    red[tid] = lsum;
    __syncthreads();
    for (int st = 128; st > 0; st >>= 1) {
        if (tid < st) red[tid] += red[tid + st];
        __syncthreads();
    }
    float inv = 1.0f / red[0];
    __syncthreads();

    const int d = tid & 63, g = tid >> 6;
    float acc = 0.f;
    for (int n = g; n < N_; n += 4)
        acc = fmaf(logits[n], v[((size_t)h * N_ + n) * D_ + d], acc);
    red[tid] = acc;
    __syncthreads();
    if (g == 0) {
        float r = red[d] + red[64 + d] + red[128 + d] + red[192 + d];
        att[(size_t)s * C_ + h * 64 + d] = r * inv;
    }
}

// ---------------------------------------------------------------------------
// Pano attention, tiled flash-style.
// Block = (ptile, vw, h); 32 q-rows share 420 dense keys + 95-row banded
// neighbor window. Online softmax; K transposed in LDS, V row-major pad-68.
// ---------------------------------------------------------------------------
__global__ __launch_bounds__(256)
void attn_pano2(const float* __restrict__ q, const float* __restrict__ k,
                const float* __restrict__ v, float* __restrict__ att)
{
    const int pt = blockIdx.x;   // 0..NTILE-1
    const int vw = blockIdx.y;   // 0..3
    const int h  = blockIdx.z;   // 0..11
    const int tid = threadIdx.x;
    const int p0 = pt * TP;
    const int nrows = (P_ - p0 < TP) ? (P_ - p0) : TP;   // 32 or 16

    __shared__ float qsT[64][TP];     // [d][r]
    __shared__ float ckT[64][NBW];    // [d][j]  (shared chunks use j<64)
    __shared__ float vsb[NBW][68];    // [j][d]  padded row
    __shared__ float Pc[TP][68];      // probs chunk (wave-local rows)

    // ---- stage Q transposed ----
    {
        int r  = tid >> 3;
        int d0 = (tid & 7) * 8;
        float4 a = make_float4(0.f,0.f,0.f,0.f), b = a;
        if (r < nrows) {
            const float* qp = q + ((size_t)h * N_ + NS_ + vw * P_ + p0 + r) * D_ + d0;
            a = *(const float4*)qp;
            b = *(const float4*)(qp + 4);
        }
        qsT[d0+0][r]=a.x; qsT[d0+1][r]=a.y; qsT[d0+2][r]=a.z; qsT[d0+3][r]=a.w;
        qsT[d0+4][r]=b.x; qsT[d0+5][r]=b.y; qsT[d0+6][r]=b.z; qsT[d0+7][r]=b.w;
    }

    const int rg = tid >> 4;     // 0..15 -> rows rg*2, rg*2+1
    const int cg = tid & 15;     // col/d group of 4
    const int r0 = rg * 2;
    const float scale = 0.125f;

    float m0 = -INFINITY, m1 = -INFINITY;
    float l0 = 0.f, l1 = 0.f;
    float o0[4] = {0.f,0.f,0.f,0.f};
    float o1[4] = {0.f,0.f,0.f,0.f};

    for (int ch = 0; ch < NCH + 2; ++ch) {
        const bool is_cross = (ch >= NCH);

        // ---- staging ----
        if (ch < NCH) {
            int j = tid & 63;
            int g = tid >> 6;
            int sj = ch * 64 + j;
            bool valid = sj < (NS_ + P_);
            int gk = (sj < NS_) ? sj : (NS_ + vw * P_ + (sj - NS_));
            #pragma unroll
            for (int q4 = 0; q4 < 4; ++q4) {
                int d0 = g * 16 + q4 * 4;
                float4 k4 = make_float4(0.f,0.f,0.f,0.f), v4 = k4;
                if (valid) {
                    k4 = *(const float4*)(k + ((size_t)h * N_ + gk) * D_ + d0);
                    v4 = *(const float4*)(v + ((size_t)h * N_ + gk) * D_ + d0);
                }
                ckT[d0+0][j]=k4.x; ckT[d0+1][j]=k4.y; ckT[d0+2][j]=k4.z; ckT[d0+3][j]=k4.w;
                *(float4*)&vsb[j][d0] = v4;
            }
        } else if (ch == NCH) {
            int cv = (vw + 1) & 3;
            int g = tid & 3;
            for (int i = tid >> 2; i < 95; i += 64) {
                int nrow = NS_ + cv * P_ + ((p0 + i) % P_);
                #pragma unroll
                for (int q4 = 0; q4 < 4; ++q4) {
                    int d0 = g * 16 + q4 * 4;
                    float4 k4 = *(const float4*)(k + ((size_t)h * N_ + nrow) * D_ + d0);
                    float4 v4 = *(const float4*)(v + ((size_t)h * N_ + nrow) * D_ + d0);
                    ckT[d0+0][i]=k4.x; ckT[d0+1][i]=k4.y; ckT[d0+2][i]=k4.z; ckT[d0+3][i]=k4.w;
                    *(float4*)&vsb[i][d0] = v4;
                }
            }
            // zero pad col 95
            if (tid < 64) ckT[tid][95] = 0.f;
            if (tid >= 64 && tid < 132) vsb[95][tid - 64] = 0.f;
        }
        __syncthreads();

        const int colbase = is_cross ? (ch - NCH) * 64 : 0;
        const int ncols   = (!is_cross) ? 64 : ((ch == NCH) ? 64 : 32);
        const int colg    = colbase + cg * 4;
        const int cl      = is_cross ? ((colg < 92) ? colg : 92) : colg;

        // ---- S: 2 rows x 4 cols per thread ----
        float s0[4] = {0.f,0.f,0.f,0.f};
        float s1[4] = {0.f,0.f,0.f,0.f};
        #pragma unroll 8
        for (int d = 0; d < 64; ++d) {
            float2 q2 = *(const float2*)&qsT[d][r0];
            float4 k4 = *(const float4*)&ckT[d][cl];
            s0[0] = fmaf(q2.x, k4.x, s0[0]); s0[1] = fmaf(q2.x, k4.y, s0[1]);
            s0[2] = fmaf(q2.x, k4.z, s0[2]); s0[3] = fmaf(q2.x, k4.w, s0[3]);
            s1[0] = fmaf(q2.y, k4.x, s1[0]); s1[1] = fmaf(q2.y, k4.y, s1[1]);
            s1[2] = fmaf(q2.y, k4.z, s1[2]); s1[3] = fmaf(q2.y, k4.w, s1[3]);
        }

        // ---- mask + scale ----
        #pragma unroll
        for (int jj = 0; jj < 4; ++jj) {
            int col = colg + jj;
            bool va, vb;
            if (!is_cross) {
                va = vb = (ch * 64 + col) < (NS_ + P_);
            } else {
                va = (unsigned)(col - (r0 + 0)) < 64u;
                vb = (unsigned)(col - (r0 + 1)) < 64u;
            }
            s0[jj] = va ? s0[jj] * scale : -INFINITY;
            s1[jj] = vb ? s1[jj] * scale : -INFINITY;
        }

        // ---- chunk row max (reduce over 16 cg lanes) ----
        float c0 = fmaxf(fmaxf(s0[0], s0[1]), fmaxf(s0[2], s0[3]));
        float c1 = fmaxf(fmaxf(s1[0], s1[1]), fmaxf(s1[2], s1[3]));
        #pragma unroll
        for (int off = 1; off < 16; off <<= 1) {
            c0 = fmaxf(c0, __shfl_xor(c0, off, 64));
            c1 = fmaxf(c1, __shfl_xor(c1, off, 64));
        }
        float nm0 = fmaxf(m0, c0), nm1 = fmaxf(m1, c1);
        float f0 = __expf(m0 - nm0), f1 = __expf(m1 - nm1);
        m0 = nm0; m1 = nm1;

        // ---- P = exp(S - m), write chunk-local, accumulate row sums ----
        float p0v[4], p1v[4];
        float ps0 = 0.f, ps1 = 0.f;
        #pragma unroll
        for (int jj = 0; jj < 4; ++jj) {
            p0v[jj] = __expf(s0[jj] - m0); ps0 += p0v[jj];
            p1v[jj] = __expf(s1[jj] - m1); ps1 += p1v[jj];
        }
        *(float4*)&Pc[r0    ][cg * 4] = make_float4(p0v[0], p0v[1], p0v[2], p0v[3]);
        *(float4*)&Pc[r0 + 1][cg * 4] = make_float4(p1v[0], p1v[1], p1v[2], p1v[3]);
        #pragma unroll
        for (int off = 1; off < 16; off <<= 1) {
            ps0 += __shfl_xor(ps0, off, 64);
            ps1 += __shfl_xor(ps1, off, 64);
        }
        l0 = l0 * f0 + ps0;
        l1 = l1 * f1 + ps1;
        #pragma unroll
        for (int t = 0; t < 4; ++t) { o0[t] *= f0; o1[t] *= f1; }

        // ---- PV: rows wave-local in Pc, V from vsb ----
        #pragma unroll 8
        for (int j = 0; j < ncols; ++j) {
            float pa = Pc[r0][j];
            float pb = Pc[r0 + 1][j];
            float4 vv = *(const float4*)&vsb[colbase + j][cg * 4];
            o0[0] = fmaf(pa, vv.x, o0[0]); o0[1] = fmaf(pa, vv.y, o0[1]);
            o0[2] = fmaf(pa, vv.z, o0[2]); o0[3] = fmaf(pa, vv.w, o0[3]);
            o1[0] = fmaf(pb, vv.x, o1[0]); o1[1] = fmaf(pb, vv.y, o1[1]);
            o1[2] = fmaf(pb, vv.z, o1[2]); o1[3] = fmaf(pb, vv.w, o1[3]);
        }
        __syncthreads();
    }

    // ---- epilogue ----
    if (r0 < nrows) {
        float inv0 = 1.0f / l0;
        float inv1 = 1.0f / l1;
        size_t row0 = (size_t)(NS_ + vw * P_ + p0 + r0);
        float4 w0 = make_float4(o0[0]*inv0, o0[1]*inv0, o0[2]*inv0, o0[3]*inv0);
        float4 w1 = make_float4(o1[0]*inv1, o1[1]*inv1, o1[2]*inv1, o1[3]*inv1);
        *(float4*)&att[row0 * C_ + h * 64 + cg * 4]       = w0;
        *(float4*)&att[(row0 + 1) * C_ + h * 64 + cg * 4] = w1;
    }
}

// ---------------------------------------------------------------------------
extern "C" void kernel_launch(void* const* d_in, const int* in_sizes, int n_in,
                              void* d_out, int out_size, void* d_ws, size_t ws_size,
                              hipStream_t stream)
{
    const float* x       = (const float*)d_in[0];
    const float* qkv_w   = (const float*)d_in[1];
    const float* qkv_b   = (const float*)d_in[2];
    const float* proj_w  = (const float*)d_in[3];
    const float* proj_b  = (const float*)d_in[4];
    float* out = (float*)d_out;

    float* ws = (float*)d_ws;
    const size_t per = (size_t)H_ * N_ * D_;
    float* q   = ws;
    float* k   = q + per;
    float* v   = k + per;
    float* att = v + per;

    dim3 g1((N_ + 63) / 64, (3 * C_) / 64);
    gemm_nt<1><<<g1, 256, 0, stream>>>(x, qkv_w, qkv_b, N_, 3 * C_, C_, q, k, v);

    attn_spatial<<<dim3(NS_, H_), 256, 0, stream>>>(q, k, v, att);

    attn_pano2<<<dim3(NTILE, V_, H_), 256, 0, stream>>>(q, k, v, att);

    dim3 g2((N_ + 63) / 64, C_ / 64);
    gemm_nt<0><<<g2, 256, 0, stream>>>(att, proj_w, proj_b, N_, C_, C_, out, nullptr, nullptr);
}

// Round 5
// 320.656 us; speedup vs baseline: 2.5321x; 1.1901x over previous
//
#include <hip/hip_runtime.h>
#include <hip/hip_bf16.h>
#include <math.h>

#define H_  12
#define N_  1620
#define D_  64
#define C_  768
#define NS_ 20
#define V_  4
#define P_  400

#define TP    32
#define NTILE 13
#define NCH   7
#define NBW   96

typedef __bf16 bf16x8 __attribute__((ext_vector_type(8)));
typedef float f32x4 __attribute__((ext_vector_type(4)));
typedef unsigned short ushort8 __attribute__((ext_vector_type(8)));
typedef unsigned short ushort4v __attribute__((ext_vector_type(4)));

struct HL { unsigned short h, l; };

// ---------------------------------------------------------------------------
// split fp32 -> bf16 hi + bf16 lo (round-to-nearest-even), bit-level
// ---------------------------------------------------------------------------
__device__ __forceinline__ unsigned short bf16_rne(float v) {
    unsigned int u = __builtin_bit_cast(unsigned int, v);
    return (unsigned short)((u + 0x7fffu + ((u >> 16) & 1u)) >> 16);
}
__device__ __forceinline__ HL split2(float v) {
    HL r;
    r.h = bf16_rne(v);
    float hf = __builtin_bit_cast(float, (unsigned int)r.h << 16);
    r.l = bf16_rne(v - hf);
    return r;
}

__global__ __launch_bounds__(256)
void split_kernel(const float* __restrict__ in, unsigned short* __restrict__ hi,
                  unsigned short* __restrict__ lo, int n4)
{
    int i = blockIdx.x * 256 + threadIdx.x;
    if (i >= n4) return;
    float4 v = ((const float4*)in)[i];
    HL a = split2(v.x), b = split2(v.y), c = split2(v.z), d = split2(v.w);
    ushort4v h, l;
    h.x = a.h; h.y = b.h; h.z = c.h; h.w = d.h;
    l.x = a.l; l.y = b.l; l.z = c.l; l.w = d.l;
    ((ushort4v*)hi)[i] = h;
    ((ushort4v*)lo)[i] = l;
}

// ---------------------------------------------------------------------------
// MFMA NT GEMM with split-2 bf16 inputs. C = A * B^T + bias.
// MODE 0: out0 row-major MxN.  MODE 1: QKV scatter into q/k/v [h][N_][D_].
// Tile 128x128, BK=32, 4 waves (2x2), 16x16x32 bf16 MFMA.
// ---------------------------------------------------------------------------
template<int MODE>
__global__ __launch_bounds__(256)
void gemm_mfma(const unsigned short* __restrict__ Ah, const unsigned short* __restrict__ Al,
               const unsigned short* __restrict__ Bh, const unsigned short* __restrict__ Bl,
               const float* __restrict__ bias, int M, int N,
               float* __restrict__ out0, float* __restrict__ out1, float* __restrict__ out2)
{
    __shared__ unsigned short Ash[2][128 * 32];
    __shared__ unsigned short Bsh[2][128 * 32];
    const int tid = threadIdx.x;
    const int tm = blockIdx.x * 128;
    const int tn = blockIdx.y * 128;
    const int lane = tid & 63;
    const int w = tid >> 6;
    const int wm = (w >> 1) * 64;
    const int wn = (w & 1) * 64;

    f32x4 acc[4][4] = {};

    const int srow = tid >> 2;          // 0..63
    const int skp  = (tid & 3) * 8;     // k element offset (0,8,16,24)

    for (int k0 = 0; k0 < 768; k0 += 32) {
        #pragma unroll
        for (int half = 0; half < 2; ++half) {
            int row = srow + half * 64;
            int gmA = tm + row; if (gmA > M - 1) gmA = M - 1;
            int gnB = tn + row;
            ushort8 va_h = *(const ushort8*)(Ah + (size_t)gmA * 768 + k0 + skp);
            ushort8 va_l = *(const ushort8*)(Al + (size_t)gmA * 768 + k0 + skp);
            ushort8 vb_h = *(const ushort8*)(Bh + (size_t)gnB * 768 + k0 + skp);
            ushort8 vb_l = *(const ushort8*)(Bl + (size_t)gnB * 768 + k0 + skp);
            *(ushort8*)&Ash[0][row * 32 + skp] = va_h;
            *(ushort8*)&Ash[1][row * 32 + skp] = va_l;
            *(ushort8*)&Bsh[0][row * 32 + skp] = vb_h;
            *(ushort8*)&Bsh[1][row * 32 + skp] = vb_l;
        }
        __syncthreads();

        const int fr = lane & 15;
        const int fk = (lane >> 4) * 8;
        bf16x8 ah[4], al[4], bh[4], bl[4];
        #pragma unroll
        for (int i = 0; i < 4; ++i) {
            ah[i] = *(const bf16x8*)&Ash[0][(wm + i * 16 + fr) * 32 + fk];
            al[i] = *(const bf16x8*)&Ash[1][(wm + i * 16 + fr) * 32 + fk];
            bh[i] = *(const bf16x8*)&Bsh[0][(wn + i * 16 + fr) * 32 + fk];
            bl[i] = *(const bf16x8*)&Bsh[1][(wn + i * 16 + fr) * 32 + fk];
        }
        #pragma unroll
        for (int mi = 0; mi < 4; ++mi)
            #pragma unroll
            for (int ni = 0; ni < 4; ++ni) {
                acc[mi][ni] = __builtin_amdgcn_mfma_f32_16x16x32_bf16(ah[mi], bh[ni], acc[mi][ni], 0, 0, 0);
                acc[mi][ni] = __builtin_amdgcn_mfma_f32_16x16x32_bf16(ah[mi], bl[ni], acc[mi][ni], 0, 0, 0);
                acc[mi][ni] = __builtin_amdgcn_mfma_f32_16x16x32_bf16(al[mi], bh[ni], acc[mi][ni], 0, 0, 0);
            }
        __syncthreads();
    }

    const int fr = lane & 15;
    const int fq = (lane >> 4) * 4;
    #pragma unroll
    for (int mi = 0; mi < 4; ++mi) {
        #pragma unroll
        for (int ni = 0; ni < 4; ++ni) {
            int n = tn + wn + ni * 16 + fr;
            float bb = bias[n];
            #pragma unroll
            for (int r = 0; r < 4; ++r) {
                int m = tm + wm + mi * 16 + fq + r;
                if (m >= M) continue;
                float val = acc[mi][ni][r] + bb;
                if (MODE == 0) {
                    out0[(size_t)m * N + n] = val;
                } else {
                    int which = n / C_;
                    int rr = n - which * C_;
                    int h = rr >> 6, d = rr & 63;
                    float* dst = (which == 0) ? out0 : (which == 1) ? out1 : out2;
                    dst[((size_t)h * N_ + m) * D_ + d] = val;
                }
            }
        }
    }
}

// ---------------------------------------------------------------------------
// Spatial attention (20 rows x 1620 keys), one block per (s, h).
// Writes att as bf16 hi/lo.
// ---------------------------------------------------------------------------
__global__ __launch_bounds__(256)
void attn_spatial(const float* __restrict__ q, const float* __restrict__ k,
                  const float* __restrict__ v,
                  unsigned short* __restrict__ atthi, unsigned short* __restrict__ attlo)
{
    const int s = blockIdx.x;
    const int h = blockIdx.y;
    const int tid = threadIdx.x;

    __shared__ float qs[64];
    __shared__ float logits[N_];
    __shared__ float red[256];

    if (tid < 64) qs[tid] = q[((size_t)h * N_ + s) * D_ + tid];
    __syncthreads();

    const float scale = 0.125f;
    for (int n = tid; n < N_; n += 256) {
        const float4* kr = (const float4*)(k + ((size_t)h * N_ + n) * D_);
        float dot = 0.f;
        #pragma unroll
        for (int i = 0; i < 16; i++) {
            float4 kv = kr[i];
            dot = fmaf(kv.x, qs[i * 4 + 0], dot);
            dot = fmaf(kv.y, qs[i * 4 + 1], dot);
            dot = fmaf(kv.z, qs[i * 4 + 2], dot);
            dot = fmaf(kv.w, qs[i * 4 + 3], dot);
        }
        logits[n] = dot * scale;
    }
    __syncthreads();

    float lmax = -INFINITY;
    for (int n = tid; n < N_; n += 256) lmax = fmaxf(lmax, logits[n]);
    red[tid] = lmax;
    __syncthreads();
    for (int st = 128; st > 0; st >>= 1) {
        if (tid < st) red[tid] = fmaxf(red[tid], red[tid + st]);
        __syncthreads();
    }
    float gmax = red[0];
    __syncthreads();

    float lsum = 0.f;
    for (int n = tid; n < N_; n += 256) {
        float e = __expf(logits[n] - gmax);
        logits[n] = e;
        lsum += e;
    }
    red[tid] = lsum;
    __syncthreads();
    for (int st = 128; st > 0; st >>= 1) {
        if (tid < st) red[tid] += red[tid + st];
        __syncthreads();
    }
    float inv = 1.0f / red[0];
    __syncthreads();

    const int d = tid & 63, g = tid >> 6;
    float acc = 0.f;
    for (int n = g; n < N_; n += 4)
        acc = fmaf(logits[n], v[((size_t)h * N_ + n) * D_ + d], acc);
    red[tid] = acc;
    __syncthreads();
    if (g == 0) {
        float r = (red[d] + red[64 + d] + red[128 + d] + red[192 + d]) * inv;
        HL hl = split2(r);
        size_t idx = (size_t)s * C_ + h * 64 + d;
        atthi[idx] = hl.h;
        attlo[idx] = hl.l;
    }
}

// ---------------------------------------------------------------------------
// Pano attention, tiled flash-style; epilogue writes bf16 hi/lo.
// ---------------------------------------------------------------------------
__global__ __launch_bounds__(256)
void attn_pano2(const float* __restrict__ q, const float* __restrict__ k,
                const float* __restrict__ v,
                unsigned short* __restrict__ atthi, unsigned short* __restrict__ attlo)
{
    const int pt = blockIdx.x;
    const int vw = blockIdx.y;
    const int h  = blockIdx.z;
    const int tid = threadIdx.x;
    const int p0 = pt * TP;
    const int nrows = (P_ - p0 < TP) ? (P_ - p0) : TP;

    __shared__ float qsT[64][TP];
    __shared__ float ckT[64][NBW];
    __shared__ float vsb[NBW][68];
    __shared__ float Pc[TP][68];

    {
        int r  = tid >> 3;
        int d0 = (tid & 7) * 8;
        float4 a = make_float4(0.f,0.f,0.f,0.f), b = a;
        if (r < nrows) {
            const float* qp = q + ((size_t)h * N_ + NS_ + vw * P_ + p0 + r) * D_ + d0;
            a = *(const float4*)qp;
            b = *(const float4*)(qp + 4);
        }
        qsT[d0+0][r]=a.x; qsT[d0+1][r]=a.y; qsT[d0+2][r]=a.z; qsT[d0+3][r]=a.w;
        qsT[d0+4][r]=b.x; qsT[d0+5][r]=b.y; qsT[d0+6][r]=b.z; qsT[d0+7][r]=b.w;
    }

    const int rg = tid >> 4;
    const int cg = tid & 15;
    const int r0 = rg * 2;
    const float scale = 0.125f;

    float m0 = -INFINITY, m1 = -INFINITY;
    float l0 = 0.f, l1 = 0.f;
    float o0[4] = {0.f,0.f,0.f,0.f};
    float o1[4] = {0.f,0.f,0.f,0.f};

    for (int ch = 0; ch < NCH + 2; ++ch) {
        const bool is_cross = (ch >= NCH);

        if (ch < NCH) {
            int j = tid & 63;
            int g = tid >> 6;
            int sj = ch * 64 + j;
            bool valid = sj < (NS_ + P_);
            int gk = (sj < NS_) ? sj : (NS_ + vw * P_ + (sj - NS_));
            #pragma unroll
            for (int q4 = 0; q4 < 4; ++q4) {
                int d0 = g * 16 + q4 * 4;
                float4 k4 = make_float4(0.f,0.f,0.f,0.f), v4 = k4;
                if (valid) {
                    k4 = *(const float4*)(k + ((size_t)h * N_ + gk) * D_ + d0);
                    v4 = *(const float4*)(v + ((size_t)h * N_ + gk) * D_ + d0);
                }
                ckT[d0+0][j]=k4.x; ckT[d0+1][j]=k4.y; ckT[d0+2][j]=k4.z; ckT[d0+3][j]=k4.w;
                *(float4*)&vsb[j][d0] = v4;
            }
        } else if (ch == NCH) {
            int cv = (vw + 1) & 3;
            int g = tid & 3;
            for (int i = tid >> 2; i < 95; i += 64) {
                int nrow = NS_ + cv * P_ + ((p0 + i) % P_);
                #pragma unroll
                for (int q4 = 0; q4 < 4; ++q4) {
                    int d0 = g * 16 + q4 * 4;
                    float4 k4 = *(const float4*)(k + ((size_t)h * N_ + nrow) * D_ + d0);
                    float4 v4 = *(const float4*)(v + ((size_t)h * N_ + nrow) * D_ + d0);
                    ckT[d0+0][i]=k4.x; ckT[d0+1][i]=k4.y; ckT[d0+2][i]=k4.z; ckT[d0+3][i]=k4.w;
                    *(float4*)&vsb[i][d0] = v4;
                }
            }
            if (tid < 64) ckT[tid][95] = 0.f;
            if (tid >= 64 && tid < 132) vsb[95][tid - 64] = 0.f;
        }
        __syncthreads();

        const int colbase = is_cross ? (ch - NCH) * 64 : 0;
        const int ncols   = (!is_cross) ? 64 : ((ch == NCH) ? 64 : 32);
        const int colg    = colbase + cg * 4;
        const int cl      = is_cross ? ((colg < 92) ? colg : 92) : colg;

        float s0[4] = {0.f,0.f,0.f,0.f};
        float s1[4] = {0.f,0.f,0.f,0.f};
        #pragma unroll 8
        for (int d = 0; d < 64; ++d) {
            float2 q2 = *(const float2*)&qsT[d][r0];
            float4 k4 = *(const float4*)&ckT[d][cl];
            s0[0] = fmaf(q2.x, k4.x, s0[0]); s0[1] = fmaf(q2.x, k4.y, s0[1]);
            s0[2] = fmaf(q2.x, k4.z, s0[2]); s0[3] = fmaf(q2.x, k4.w, s0[3]);
            s1[0] = fmaf(q2.y, k4.x, s1[0]); s1[1] = fmaf(q2.y, k4.y, s1[1]);
            s1[2] = fmaf(q2.y, k4.z, s1[2]); s1[3] = fmaf(q2.y, k4.w, s1[3]);
        }

        #pragma unroll
        for (int jj = 0; jj < 4; ++jj) {
            int col = colg + jj;
            bool va, vb;
            if (!is_cross) {
                va = vb = (ch * 64 + col) < (NS_ + P_);
            } else {
                va = (unsigned)(col - (r0 + 0)) < 64u;
                vb = (unsigned)(col - (r0 + 1)) < 64u;
            }
            s0[jj] = va ? s0[jj] * scale : -INFINITY;
            s1[jj] = vb ? s1[jj] * scale : -INFINITY;
        }

        float c0 = fmaxf(fmaxf(s0[0], s0[1]), fmaxf(s0[2], s0[3]));
        float c1 = fmaxf(fmaxf(s1[0], s1[1]), fmaxf(s1[2], s1[3]));
        #pragma unroll
        for (int off = 1; off < 16; off <<= 1) {
            c0 = fmaxf(c0, __shfl_xor(c0, off, 64));
            c1 = fmaxf(c1, __shfl_xor(c1, off, 64));
        }
        float nm0 = fmaxf(m0, c0), nm1 = fmaxf(m1, c1);
        float f0 = __expf(m0 - nm0), f1 = __expf(m1 - nm1);
        m0 = nm0; m1 = nm1;

        float p0v[4], p1v[4];
        float ps0 = 0.f, ps1 = 0.f;
        #pragma unroll
        for (int jj = 0; jj < 4; ++jj) {
            p0v[jj] = __expf(s0[jj] - m0); ps0 += p0v[jj];
            p1v[jj] = __expf(s1[jj] - m1); ps1 += p1v[jj];
        }
        *(float4*)&Pc[r0    ][cg * 4] = make_float4(p0v[0], p0v[1], p0v[2], p0v[3]);
        *(float4*)&Pc[r0 + 1][cg * 4] = make_float4(p1v[0], p1v[1], p1v[2], p1v[3]);
        #pragma unroll
        for (int off = 1; off < 16; off <<= 1) {
            ps0 += __shfl_xor(ps0, off, 64);
            ps1 += __shfl_xor(ps1, off, 64);
        }
        l0 = l0 * f0 + ps0;
        l1 = l1 * f1 + ps1;
        #pragma unroll
        for (int t = 0; t < 4; ++t) { o0[t] *= f0; o1[t] *= f1; }

        #pragma unroll 8
        for (int j = 0; j < ncols; ++j) {
            float pa = Pc[r0][j];
            float pb = Pc[r0 + 1][j];
            float4 vv = *(const float4*)&vsb[colbase + j][cg * 4];
            o0[0] = fmaf(pa, vv.x, o0[0]); o0[1] = fmaf(pa, vv.y, o0[1]);
            o0[2] = fmaf(pa, vv.z, o0[2]); o0[3] = fmaf(pa, vv.w, o0[3]);
            o1[0] = fmaf(pb, vv.x, o1[0]); o1[1] = fmaf(pb, vv.y, o1[1]);
            o1[2] = fmaf(pb, vv.z, o1[2]); o1[3] = fmaf(pb, vv.w, o1[3]);
        }
        __syncthreads();
    }

    if (r0 < nrows) {
        float inv0 = 1.0f / l0;
        float inv1 = 1.0f / l1;
        size_t row0 = (size_t)(NS_ + vw * P_ + p0 + r0);
        size_t base0 = row0 * C_ + h * 64 + cg * 4;
        size_t base1 = (row0 + 1) * C_ + h * 64 + cg * 4;
        HL a0 = split2(o0[0]*inv0), a1 = split2(o0[1]*inv0),
           a2 = split2(o0[2]*inv0), a3 = split2(o0[3]*inv0);
        HL b0 = split2(o1[0]*inv1), b1 = split2(o1[1]*inv1),
           b2 = split2(o1[2]*inv1), b3 = split2(o1[3]*inv1);
        ushort4v h0, l0v, h1, l1v;
        h0.x=a0.h; h0.y=a1.h; h0.z=a2.h; h0.w=a3.h;
        l0v.x=a0.l; l0v.y=a1.l; l0v.z=a2.l; l0v.w=a3.l;
        h1.x=b0.h; h1.y=b1.h; h1.z=b2.h; h1.w=b3.h;
        l1v.x=b0.l; l1v.y=b1.l; l1v.z=b2.l; l1v.w=b3.l;
        *(ushort4v*)&atthi[base0] = h0; *(ushort4v*)&attlo[base0] = l0v;
        *(ushort4v*)&atthi[base1] = h1; *(ushort4v*)&attlo[base1] = l1v;
    }
}

// ---------------------------------------------------------------------------
extern "C" void kernel_launch(void* const* d_in, const int* in_sizes, int n_in,
                              void* d_out, int out_size, void* d_ws, size_t ws_size,
                              hipStream_t stream)
{
    const float* x       = (const float*)d_in[0];
    const float* qkv_w   = (const float*)d_in[1];
    const float* qkv_b   = (const float*)d_in[2];
    const float* proj_w  = (const float*)d_in[3];
    const float* proj_b  = (const float*)d_in[4];
    float* out = (float*)d_out;

    const size_t per = (size_t)H_ * N_ * D_;        // 1,244,160
    float* q = (float*)d_ws;
    float* k = q + per;
    float* v = k + per;
    unsigned short* xhi  = (unsigned short*)(v + per);
    unsigned short* xlo  = xhi + (size_t)N_ * C_;
    unsigned short* whi  = xlo + (size_t)N_ * C_;
    unsigned short* wlo  = whi + (size_t)3 * C_ * C_;
    unsigned short* pwhi = wlo + (size_t)3 * C_ * C_;
    unsigned short* pwlo = pwhi + (size_t)C_ * C_;
    unsigned short* atthi = pwlo + (size_t)C_ * C_;
    unsigned short* attlo = atthi + (size_t)N_ * C_;

    // 0) split inputs to bf16 hi/lo
    {
        int n4 = (N_ * C_) / 4;
        split_kernel<<<(n4 + 255) / 256, 256, 0, stream>>>(x, xhi, xlo, n4);
        n4 = (3 * C_ * C_) / 4;
        split_kernel<<<(n4 + 255) / 256, 256, 0, stream>>>(qkv_w, whi, wlo, n4);
        n4 = (C_ * C_) / 4;
        split_kernel<<<(n4 + 255) / 256, 256, 0, stream>>>(proj_w, pwhi, pwlo, n4);
    }

    // 1) QKV projection (MFMA), scatter into q/k/v [h][n][d]
    dim3 g1((N_ + 127) / 128, (3 * C_) / 128);   // 13 x 18
    gemm_mfma<1><<<g1, 256, 0, stream>>>(xhi, xlo, whi, wlo, qkv_b, N_, 3 * C_, q, k, v);

    // 2) spatial attention rows
    attn_spatial<<<dim3(NS_, H_), 256, 0, stream>>>(q, k, v, atthi, attlo);

    // 3) panoramic attention rows
    attn_pano2<<<dim3(NTILE, V_, H_), 256, 0, stream>>>(q, k, v, atthi, attlo);

    // 4) output projection (MFMA)
    dim3 g2((N_ + 127) / 128, C_ / 128);         // 13 x 6
    gemm_mfma<0><<<g2, 256, 0, stream>>>(atthi, attlo, pwhi, pwlo, proj_b, N_, C_, out, nullptr, nullptr);
}

// Round 6
// 266.067 us; speedup vs baseline: 3.0516x; 1.2052x over previous
//
#include <hip/hip_runtime.h>
#include <hip/hip_bf16.h>
#include <math.h>

#define H_  12
#define N_  1620
#define D_  64
#define C_  768
#define NS_ 20
#define V_  4
#define P_  400

#define TPP    64
#define PTILES 7    // ceil(400/64)

typedef __bf16 bf16x8 __attribute__((ext_vector_type(8)));
typedef float f32x4 __attribute__((ext_vector_type(4)));
typedef unsigned short ushort8 __attribute__((ext_vector_type(8)));
typedef unsigned short ushort4v __attribute__((ext_vector_type(4)));
typedef unsigned int uint4v __attribute__((ext_vector_type(4)));

struct HL { unsigned short h, l; };

__device__ __forceinline__ unsigned short bf16_rne(float v) {
    unsigned int u = __builtin_bit_cast(unsigned int, v);
    return (unsigned short)((u + 0x7fffu + ((u >> 16) & 1u)) >> 16);
}
__device__ __forceinline__ HL split2(float v) {
    HL r;
    r.h = bf16_rne(v);
    float hf = __builtin_bit_cast(float, (unsigned int)r.h << 16);
    r.l = bf16_rne(v - hf);
    return r;
}
__device__ __forceinline__ float unpk(unsigned int u) {
    return __builtin_bit_cast(float, u & 0xffff0000u) + __builtin_bit_cast(float, u << 16);
}
// 8 packed u32 -> hi bf16x8 (high halves), lo bf16x8 (low halves)
__device__ __forceinline__ void unpack8(uint4v a, uint4v b, bf16x8& hi, bf16x8& lo) {
    ushort8 ea = __builtin_bit_cast(ushort8, a);
    ushort8 eb = __builtin_bit_cast(ushort8, b);
    hi = __builtin_bit_cast(bf16x8, __builtin_shufflevector(ea, eb, 1,3,5,7,9,11,13,15));
    lo = __builtin_bit_cast(bf16x8, __builtin_shufflevector(ea, eb, 0,2,4,6,8,10,12,14));
}

__global__ __launch_bounds__(256)
void split_kernel(const float* __restrict__ in, unsigned short* __restrict__ hi,
                  unsigned short* __restrict__ lo, int n4)
{
    int i = blockIdx.x * 256 + threadIdx.x;
    if (i >= n4) return;
    float4 v = ((const float4*)in)[i];
    HL a = split2(v.x), b = split2(v.y), c = split2(v.z), d = split2(v.w);
    ushort4v h, l;
    h.x = a.h; h.y = b.h; h.z = c.h; h.w = d.h;
    l.x = a.l; l.y = b.l; l.z = c.l; l.w = d.l;
    ((ushort4v*)hi)[i] = h;
    ((ushort4v*)lo)[i] = l;
}

// ---------------------------------------------------------------------------
// MFMA NT GEMM with split-2 bf16 inputs. C = A * B^T + bias.
// MODE 0: out0 row-major MxN (f32).
// MODE 1: QKV scatter; writes PACKED u32 (hi<<16|lo) into q/k/v [h][N_][D_].
// ---------------------------------------------------------------------------
template<int MODE>
__global__ __launch_bounds__(256)
void gemm_mfma(const unsigned short* __restrict__ Ah, const unsigned short* __restrict__ Al,
               const unsigned short* __restrict__ Bh, const unsigned short* __restrict__ Bl,
               const float* __restrict__ bias, int M, int N,
               float* __restrict__ out0, float* __restrict__ out1, float* __restrict__ out2)
{
    __shared__ unsigned short Ash[2][128 * 32];
    __shared__ unsigned short Bsh[2][128 * 32];
    const int tid = threadIdx.x;
    const int tm = blockIdx.x * 128;
    const int tn = blockIdx.y * 128;
    const int lane = tid & 63;
    const int w = tid >> 6;
    const int wm = (w >> 1) * 64;
    const int wn = (w & 1) * 64;

    f32x4 acc[4][4] = {};

    const int srow = tid >> 2;
    const int skp  = (tid & 3) * 8;

    for (int k0 = 0; k0 < 768; k0 += 32) {
        #pragma unroll
        for (int half = 0; half < 2; ++half) {
            int row = srow + half * 64;
            int gmA = tm + row; if (gmA > M - 1) gmA = M - 1;
            int gnB = tn + row;
            ushort8 va_h = *(const ushort8*)(Ah + (size_t)gmA * 768 + k0 + skp);
            ushort8 va_l = *(const ushort8*)(Al + (size_t)gmA * 768 + k0 + skp);
            ushort8 vb_h = *(const ushort8*)(Bh + (size_t)gnB * 768 + k0 + skp);
            ushort8 vb_l = *(const ushort8*)(Bl + (size_t)gnB * 768 + k0 + skp);
            *(ushort8*)&Ash[0][row * 32 + skp] = va_h;
            *(ushort8*)&Ash[1][row * 32 + skp] = va_l;
            *(ushort8*)&Bsh[0][row * 32 + skp] = vb_h;
            *(ushort8*)&Bsh[1][row * 32 + skp] = vb_l;
        }
        __syncthreads();

        const int fr = lane & 15;
        const int fk = (lane >> 4) * 8;
        bf16x8 ah[4], al[4], bh[4], bl[4];
        #pragma unroll
        for (int i = 0; i < 4; ++i) {
            ah[i] = *(const bf16x8*)&Ash[0][(wm + i * 16 + fr) * 32 + fk];
            al[i] = *(const bf16x8*)&Ash[1][(wm + i * 16 + fr) * 32 + fk];
            bh[i] = *(const bf16x8*)&Bsh[0][(wn + i * 16 + fr) * 32 + fk];
            bl[i] = *(const bf16x8*)&Bsh[1][(wn + i * 16 + fr) * 32 + fk];
        }
        #pragma unroll
        for (int mi = 0; mi < 4; ++mi)
            #pragma unroll
            for (int ni = 0; ni < 4; ++ni) {
                acc[mi][ni] = __builtin_amdgcn_mfma_f32_16x16x32_bf16(ah[mi], bh[ni], acc[mi][ni], 0, 0, 0);
                acc[mi][ni] = __builtin_amdgcn_mfma_f32_16x16x32_bf16(ah[mi], bl[ni], acc[mi][ni], 0, 0, 0);
                acc[mi][ni] = __builtin_amdgcn_mfma_f32_16x16x32_bf16(al[mi], bh[ni], acc[mi][ni], 0, 0, 0);
            }
        __syncthreads();
    }

    const int fr = lane & 15;
    const int fq = (lane >> 4) * 4;
    #pragma unroll
    for (int mi = 0; mi < 4; ++mi) {
        #pragma unroll
        for (int ni = 0; ni < 4; ++ni) {
            int n = tn + wn + ni * 16 + fr;
            float bb = bias[n];
            #pragma unroll
            for (int r = 0; r < 4; ++r) {
                int m = tm + wm + mi * 16 + fq + r;
                if (m >= M) continue;
                float val = acc[mi][ni][r] + bb;
                if (MODE == 0) {
                    out0[(size_t)m * N + n] = val;
                } else {
                    int which = n / C_;
                    int rr = n - which * C_;
                    int h = rr >> 6, d = rr & 63;
                    float* dst = (which == 0) ? out0 : (which == 1) ? out1 : out2;
                    HL hl2 = split2(val);
                    ((unsigned int*)dst)[((size_t)h * N_ + m) * D_ + d] =
                        ((unsigned int)hl2.h << 16) | hl2.l;
                }
            }
        }
    }
}

// ---------------------------------------------------------------------------
// Spatial attention (20 rows x 1620 keys), one block per (s, h).
// Inputs packed u32 (hi|lo); writes att as bf16 hi/lo.
// ---------------------------------------------------------------------------
__global__ __launch_bounds__(256)
void attn_spatial(const unsigned int* __restrict__ qp, const unsigned int* __restrict__ kp,
                  const unsigned int* __restrict__ vp,
                  unsigned short* __restrict__ atthi, unsigned short* __restrict__ attlo)
{
    const int s = blockIdx.x;
    const int h = blockIdx.y;
    const int tid = threadIdx.x;

    __shared__ float qs[64];
    __shared__ float logits[N_];
    __shared__ float red[256];

    if (tid < 64) qs[tid] = unpk(qp[(((size_t)h * N_ + s) << 6) + tid]);
    __syncthreads();

    const float scale = 0.125f;
    for (int n = tid; n < N_; n += 256) {
        const uint4v* kr = (const uint4v*)(kp + (((size_t)h * N_ + n) << 6));
        float dot = 0.f;
        #pragma unroll
        for (int i = 0; i < 16; i++) {
            uint4v kv = kr[i];
            dot = fmaf(unpk(kv.x), qs[i * 4 + 0], dot);
            dot = fmaf(unpk(kv.y), qs[i * 4 + 1], dot);
            dot = fmaf(unpk(kv.z), qs[i * 4 + 2], dot);
            dot = fmaf(unpk(kv.w), qs[i * 4 + 3], dot);
        }
        logits[n] = dot * scale;
    }
    __syncthreads();

    float lmax = -INFINITY;
    for (int n = tid; n < N_; n += 256) lmax = fmaxf(lmax, logits[n]);
    red[tid] = lmax;
    __syncthreads();
    for (int st = 128; st > 0; st >>= 1) {
        if (tid < st) red[tid] = fmaxf(red[tid], red[tid + st]);
        __syncthreads();
    }
    float gmax = red[0];
    __syncthreads();

    float lsum = 0.f;
    for (int n = tid; n < N_; n += 256) {
        float e = __expf(logits[n] - gmax);
        logits[n] = e;
        lsum += e;
    }
    red[tid] = lsum;
    __syncthreads();
    for (int st = 128; st > 0; st >>= 1) {
        if (tid < st) red[tid] += red[tid + st];
        __syncthreads();
    }
    float inv = 1.0f / red[0];
    __syncthreads();

    const int d = tid & 63, g = tid >> 6;
    float acc = 0.f;
    for (int n = g; n < N_; n += 4)
        acc = fmaf(logits[n], unpk(vp[(((size_t)h * N_ + n) << 6) + d]), acc);
    red[tid] = acc;
    __syncthreads();
    if (g == 0) {
        float r = (red[d] + red[64 + d] + red[128 + d] + red[192 + d]) * inv;
        HL hl = split2(r);
        size_t idx = (size_t)s * C_ + h * 64 + d;
        atthi[idx] = hl.h;
        attlo[idx] = hl.l;
    }
}

// ---------------------------------------------------------------------------
// Pano attention, MFMA flash-style. Block = 64 q-rows of one (h, vw).
// 4 waves x 16 rows. 9 chunks of 64 keys (7 shared + 2 cross-window).
// K staged [key][d], V transposed [d][key], P reuses K buffer; all packed
// u32 hi/lo bf16 with 8-elem XOR swizzle for <=4-way LDS banking.
// ---------------------------------------------------------------------------
__global__ __launch_bounds__(256)
void attn_pano3(const unsigned int* __restrict__ qp, const unsigned int* __restrict__ kp,
                const unsigned int* __restrict__ vp,
                unsigned short* __restrict__ atthi, unsigned short* __restrict__ attlo)
{
    const int pt = blockIdx.x, vw = blockIdx.y, h = blockIdx.z;
    const int tid = threadIdx.x;
    const int lane = tid & 63;
    const int w = tid >> 6;
    const int p0 = pt * TPP;
    const int wr = w * 16;
    const int cv = (vw + 1) & 3;
    const int c = lane & 15;
    const int g = lane >> 4;

    __shared__ unsigned int Kl[64][68];   // K chunk, then reused for P
    __shared__ unsigned int VT[64][68];   // V^T chunk

    // persistent Q A-frags (2 k-steps of 32)
    bf16x8 qh[2], ql[2];
    {
        int row = NS_ + vw * P_ + p0 + wr + c;
        if (row > N_ - 1) row = N_ - 1;
        const unsigned int* qrow = qp + (((size_t)h * N_ + row) << 6);
        #pragma unroll
        for (int ss = 0; ss < 2; ++ss) {
            uint4v u0 = *(const uint4v*)(qrow + ss * 32 + g * 8);
            uint4v u1 = *(const uint4v*)(qrow + ss * 32 + g * 8 + 4);
            unpack8(u0, u1, qh[ss], ql[ss]);
        }
    }

    float m[4], l[4];
    f32x4 o[4] = {};
    #pragma unroll
    for (int r = 0; r < 4; ++r) { m[r] = -INFINITY; l[r] = 0.f; }

    for (int ch = 0; ch < 9; ++ch) {
        // ---- stage K [key][d^swz] ----
        #pragma unroll
        for (int i = 0; i < 4; ++i) {
            int f = i * 256 + tid;
            int key = f >> 4, dq = (f & 15) << 2;
            int n;
            if (ch < 7) {
                int sj = ch * 64 + key;
                n = (sj < NS_) ? sj : (NS_ + vw * P_ + (sj - NS_));
                if (sj >= NS_ + P_) n = 0;
            } else {
                int pp = p0 + (ch - 7) * 64 + key;
                if (pp >= P_) pp -= P_;
                if (pp >= P_) pp -= P_;
                n = NS_ + cv * P_ + pp;
            }
            uint4v kv = *(const uint4v*)(kp + (((size_t)h * N_ + n) << 6) + dq);
            *(uint4v*)&Kl[key][dq ^ (8 * (key & 3))] = kv;
        }
        // ---- stage V transposed [d][key^swz] (4x4 reg transpose) ----
        {
            int kg = (tid & 15) << 2;
            int dq = (tid >> 4) << 2;
            uint4v rr[4];
            #pragma unroll
            for (int t = 0; t < 4; ++t) {
                int key = kg + t;
                int n;
                if (ch < 7) {
                    int sj = ch * 64 + key;
                    n = (sj < NS_) ? sj : (NS_ + vw * P_ + (sj - NS_));
                    if (sj >= NS_ + P_) n = 0;
                } else {
                    int pp = p0 + (ch - 7) * 64 + key;
                    if (pp >= P_) pp -= P_;
                    if (pp >= P_) pp -= P_;
                    n = NS_ + cv * P_ + pp;
                }
                rr[t] = *(const uint4v*)(vp + (((size_t)h * N_ + n) << 6) + dq);
            }
            #pragma unroll
            for (int j = 0; j < 4; ++j) {
                uint4v wv;
                wv.x = rr[0][j]; wv.y = rr[1][j]; wv.z = rr[2][j]; wv.w = rr[3][j];
                *(uint4v*)&VT[dq + j][kg ^ (8 * j)] = wv;
            }
        }
        __syncthreads();

        // ---- QK^T: S[16 rows][64 keys] per wave ----
        f32x4 s[4] = {};
        #pragma unroll
        for (int ss = 0; ss < 2; ++ss) {
            #pragma unroll
            for (int nf = 0; nf < 4; ++nf) {
                int key = nf * 16 + c;
                int db = (ss * 32 + g * 8) ^ (8 * (key & 3));
                uint4v u0 = *(const uint4v*)&Kl[key][db];
                uint4v u1 = *(const uint4v*)&Kl[key][db + 4];
                bf16x8 kh, klv;
                unpack8(u0, u1, kh, klv);
                s[nf] = __builtin_amdgcn_mfma_f32_16x16x32_bf16(qh[ss], kh,  s[nf], 0, 0, 0);
                s[nf] = __builtin_amdgcn_mfma_f32_16x16x32_bf16(qh[ss], klv, s[nf], 0, 0, 0);
                s[nf] = __builtin_amdgcn_mfma_f32_16x16x32_bf16(ql[ss], kh,  s[nf], 0, 0, 0);
            }
        }

        // ---- mask + scale ----
        #pragma unroll
        for (int nf = 0; nf < 4; ++nf) {
            int col = nf * 16 + c;
            #pragma unroll
            for (int r = 0; r < 4; ++r) {
                int rowl = wr + g * 4 + r;
                bool valid;
                if (ch < 7) {
                    valid = (ch * 64 + col) < (NS_ + P_);
                } else {
                    int i = (ch - 7) * 64 + col;
                    valid = (i < 127) && ((unsigned)(i - rowl) < 64u);
                }
                s[nf][r] = valid ? s[nf][r] * 0.125f : -INFINITY;
            }
        }

        // ---- online softmax (rows live in 16-lane groups) ----
        float fct[4];
        #pragma unroll
        for (int r = 0; r < 4; ++r) {
            float cm = fmaxf(fmaxf(s[0][r], s[1][r]), fmaxf(s[2][r], s[3][r]));
            cm = fmaxf(cm, __shfl_xor(cm, 1, 64));
            cm = fmaxf(cm, __shfl_xor(cm, 2, 64));
            cm = fmaxf(cm, __shfl_xor(cm, 4, 64));
            cm = fmaxf(cm, __shfl_xor(cm, 8, 64));
            float nm = fmaxf(m[r], cm);
            fct[r] = __expf(m[r] - nm);
            m[r] = nm;
        }

        __syncthreads();   // all waves finished reading Kl as K

        float ps[4] = {0.f, 0.f, 0.f, 0.f};
        #pragma unroll
        for (int nf = 0; nf < 4; ++nf) {
            #pragma unroll
            for (int r = 0; r < 4; ++r) {
                float p = __expf(s[nf][r] - m[r]);
                ps[r] += p;
                HL hl2 = split2(p);
                int rowl = wr + g * 4 + r;
                int col = (nf * 16 + c) ^ (8 * (rowl & 3));
                Kl[rowl][col] = ((unsigned int)hl2.h << 16) | hl2.l;
            }
        }
        #pragma unroll
        for (int r = 0; r < 4; ++r) {
            ps[r] += __shfl_xor(ps[r], 1, 64);
            ps[r] += __shfl_xor(ps[r], 2, 64);
            ps[r] += __shfl_xor(ps[r], 4, 64);
            ps[r] += __shfl_xor(ps[r], 8, 64);
            l[r] = l[r] * fct[r] + ps[r];
        }
        #pragma unroll
        for (int nf = 0; nf < 4; ++nf)
            #pragma unroll
            for (int r = 0; r < 4; ++r)
                o[nf][r] *= fct[r];

        // ---- P A-frags (wave-local rows; same-wave LDS RAW, no barrier) ----
        bf16x8 pah[2], pal[2];
        {
            int prow = wr + c;
            int xw = 8 * (prow & 3);
            #pragma unroll
            for (int ss = 0; ss < 2; ++ss) {
                int kb = (ss * 32 + g * 8) ^ xw;
                uint4v u0 = *(const uint4v*)&Kl[prow][kb];
                uint4v u1 = *(const uint4v*)&Kl[prow][kb + 4];
                unpack8(u0, u1, pah[ss], pal[ss]);
            }
        }

        // ---- PV ----
        int xv = 8 * (c & 3);
        #pragma unroll
        for (int ss = 0; ss < 2; ++ss) {
            #pragma unroll
            for (int nf = 0; nf < 4; ++nf) {
                int d = nf * 16 + c;
                int kb = (ss * 32 + g * 8) ^ xv;
                uint4v u0 = *(const uint4v*)&VT[d][kb];
                uint4v u1 = *(const uint4v*)&VT[d][kb + 4];
                bf16x8 vh, vl;
                unpack8(u0, u1, vh, vl);
                o[nf] = __builtin_amdgcn_mfma_f32_16x16x32_bf16(pah[ss], vh, o[nf], 0, 0, 0);
                o[nf] = __builtin_amdgcn_mfma_f32_16x16x32_bf16(pah[ss], vl, o[nf], 0, 0, 0);
                o[nf] = __builtin_amdgcn_mfma_f32_16x16x32_bf16(pal[ss], vh, o[nf], 0, 0, 0);
            }
        }
        __syncthreads();   // before next chunk overwrites Kl / VT
    }

    // ---- epilogue ----
    #pragma unroll
    for (int r = 0; r < 4; ++r) {
        int rowl = wr + g * 4 + r;
        int prow = p0 + rowl;
        if (prow >= P_) continue;
        float inv = 1.0f / l[r];
        size_t base = ((size_t)(NS_ + vw * P_ + prow)) * C_ + h * 64 + c;
        #pragma unroll
        for (int nf = 0; nf < 4; ++nf) {
            HL hl2 = split2(o[nf][r] * inv);
            atthi[base + nf * 16] = hl2.h;
            attlo[base + nf * 16] = hl2.l;
        }
    }
}

// ---------------------------------------------------------------------------
extern "C" void kernel_launch(void* const* d_in, const int* in_sizes, int n_in,
                              void* d_out, int out_size, void* d_ws, size_t ws_size,
                              hipStream_t stream)
{
    const float* x       = (const float*)d_in[0];
    const float* qkv_w   = (const float*)d_in[1];
    const float* qkv_b   = (const float*)d_in[2];
    const float* proj_w  = (const float*)d_in[3];
    const float* proj_b  = (const float*)d_in[4];
    float* out = (float*)d_out;

    const size_t per = (size_t)H_ * N_ * D_;        // 1,244,160
    unsigned int* qp = (unsigned int*)d_ws;
    unsigned int* kp = qp + per;
    unsigned int* vp = kp + per;
    unsigned short* xhi  = (unsigned short*)(vp + per);
    unsigned short* xlo  = xhi + (size_t)N_ * C_;
    unsigned short* whi  = xlo + (size_t)N_ * C_;
    unsigned short* wlo  = whi + (size_t)3 * C_ * C_;
    unsigned short* pwhi = wlo + (size_t)3 * C_ * C_;
    unsigned short* pwlo = pwhi + (size_t)C_ * C_;
    unsigned short* atthi = pwlo + (size_t)C_ * C_;
    unsigned short* attlo = atthi + (size_t)N_ * C_;

    // 0) split inputs to bf16 hi/lo
    {
        int n4 = (N_ * C_) / 4;
        split_kernel<<<(n4 + 255) / 256, 256, 0, stream>>>(x, xhi, xlo, n4);
        n4 = (3 * C_ * C_) / 4;
        split_kernel<<<(n4 + 255) / 256, 256, 0, stream>>>(qkv_w, whi, wlo, n4);
        n4 = (C_ * C_) / 4;
        split_kernel<<<(n4 + 255) / 256, 256, 0, stream>>>(proj_w, pwhi, pwlo, n4);
    }

    // 1) QKV projection (MFMA), packed-u32 scatter into q/k/v [h][n][d]
    dim3 g1((N_ + 127) / 128, (3 * C_) / 128);   // 13 x 18
    gemm_mfma<1><<<g1, 256, 0, stream>>>(xhi, xlo, whi, wlo, qkv_b, N_, 3 * C_,
                                         (float*)qp, (float*)kp, (float*)vp);

    // 2) spatial attention rows
    attn_spatial<<<dim3(NS_, H_), 256, 0, stream>>>(qp, kp, vp, atthi, attlo);

    // 3) panoramic attention rows (MFMA flash)
    attn_pano3<<<dim3(PTILES, V_, H_), 256, 0, stream>>>(qp, kp, vp, atthi, attlo);

    // 4) output projection (MFMA)
    dim3 g2((N_ + 127) / 128, C_ / 128);         // 13 x 6
    gemm_mfma<0><<<g2, 256, 0, stream>>>(atthi, attlo, pwhi, pwlo, proj_b, N_, C_, out, nullptr, nullptr);
}

// Round 7
// 165.845 us; speedup vs baseline: 4.8957x; 1.6043x over previous
//
#include <hip/hip_runtime.h>
#include <hip/hip_bf16.h>
#include <math.h>

#define H_  12
#define N_  1620
#define D_  64
#define C_  768
#define NS_ 20
#define V_  4
#define P_  400

#define TPP    64
#define PTILES 7    // ceil(400/64)
#define SPL    26   // spatial key splits of 64 (26*64 = 1664 >= 1620)

typedef __bf16 bf16x8 __attribute__((ext_vector_type(8)));
typedef float f32x4 __attribute__((ext_vector_type(4)));
typedef unsigned short ushort8 __attribute__((ext_vector_type(8)));
typedef unsigned short ushort4v __attribute__((ext_vector_type(4)));
typedef unsigned int uint4v __attribute__((ext_vector_type(4)));

struct HL { unsigned short h, l; };

__device__ __forceinline__ unsigned short bf16_rne(float v) {
    unsigned int u = __builtin_bit_cast(unsigned int, v);
    return (unsigned short)((u + 0x7fffu + ((u >> 16) & 1u)) >> 16);
}
__device__ __forceinline__ HL split2(float v) {
    HL r;
    r.h = bf16_rne(v);
    float hf = __builtin_bit_cast(float, (unsigned int)r.h << 16);
    r.l = bf16_rne(v - hf);
    return r;
}
__device__ __forceinline__ float unpk(unsigned int u) {
    return __builtin_bit_cast(float, u & 0xffff0000u) + __builtin_bit_cast(float, u << 16);
}
__device__ __forceinline__ void unpack8(uint4v a, uint4v b, bf16x8& hi, bf16x8& lo) {
    ushort8 ea = __builtin_bit_cast(ushort8, a);
    ushort8 eb = __builtin_bit_cast(ushort8, b);
    hi = __builtin_bit_cast(bf16x8, __builtin_shufflevector(ea, eb, 1,3,5,7,9,11,13,15));
    lo = __builtin_bit_cast(bf16x8, __builtin_shufflevector(ea, eb, 0,2,4,6,8,10,12,14));
}

// ---------------------------------------------------------------------------
// One fused split kernel for x, qkv_w, proj_w.
// ---------------------------------------------------------------------------
#define N4_X  ((N_ * C_) / 4)
#define N4_W  ((3 * C_ * C_) / 4)
#define N4_PW ((C_ * C_) / 4)

__global__ __launch_bounds__(256)
void split_all(const float* __restrict__ x, const float* __restrict__ w,
               const float* __restrict__ pw,
               unsigned short* __restrict__ xhi, unsigned short* __restrict__ xlo,
               unsigned short* __restrict__ whi, unsigned short* __restrict__ wlo,
               unsigned short* __restrict__ pwhi, unsigned short* __restrict__ pwlo)
{
    int i = blockIdx.x * 256 + threadIdx.x;
    const float* src; unsigned short* dh; unsigned short* dl; int idx;
    if (i < N4_X)                { src = x;  dh = xhi;  dl = xlo;  idx = i; }
    else if (i < N4_X + N4_W)    { src = w;  dh = whi;  dl = wlo;  idx = i - N4_X; }
    else if (i < N4_X + N4_W + N4_PW) { src = pw; dh = pwhi; dl = pwlo; idx = i - N4_X - N4_W; }
    else return;
    float4 v = ((const float4*)src)[idx];
    HL a = split2(v.x), b = split2(v.y), c = split2(v.z), d = split2(v.w);
    ushort4v h, l;
    h.x = a.h; h.y = b.h; h.z = c.h; h.w = d.h;
    l.x = a.l; l.y = b.l; l.z = c.l; l.w = d.l;
    ((ushort4v*)dh)[idx] = h;
    ((ushort4v*)dl)[idx] = l;
}

// ---------------------------------------------------------------------------
// MFMA NT GEMM with split-2 bf16 inputs. C = A * B^T + bias.
// MODE 0: out0 row-major MxN (f32).
// MODE 1: QKV scatter; writes PACKED u32 (hi<<16|lo) into q/k/v [h][N_][D_].
// ---------------------------------------------------------------------------
template<int MODE>
__global__ __launch_bounds__(256)
void gemm_mfma(const unsigned short* __restrict__ Ah, const unsigned short* __restrict__ Al,
               const unsigned short* __restrict__ Bh, const unsigned short* __restrict__ Bl,
               const float* __restrict__ bias, int M, int N,
               float* __restrict__ out0, float* __restrict__ out1, float* __restrict__ out2)
{
    __shared__ unsigned short Ash[2][128 * 32];
    __shared__ unsigned short Bsh[2][128 * 32];
    const int tid = threadIdx.x;
    const int tm = blockIdx.x * 128;
    const int tn = blockIdx.y * 128;
    const int lane = tid & 63;
    const int w = tid >> 6;
    const int wm = (w >> 1) * 64;
    const int wn = (w & 1) * 64;

    f32x4 acc[4][4] = {};

    const int srow = tid >> 2;
    const int skp  = (tid & 3) * 8;

    for (int k0 = 0; k0 < 768; k0 += 32) {
        #pragma unroll
        for (int half = 0; half < 2; ++half) {
            int row = srow + half * 64;
            int gmA = tm + row; if (gmA > M - 1) gmA = M - 1;
            int gnB = tn + row;
            ushort8 va_h = *(const ushort8*)(Ah + (size_t)gmA * 768 + k0 + skp);
            ushort8 va_l = *(const ushort8*)(Al + (size_t)gmA * 768 + k0 + skp);
            ushort8 vb_h = *(const ushort8*)(Bh + (size_t)gnB * 768 + k0 + skp);
            ushort8 vb_l = *(const ushort8*)(Bl + (size_t)gnB * 768 + k0 + skp);
            *(ushort8*)&Ash[0][row * 32 + skp] = va_h;
            *(ushort8*)&Ash[1][row * 32 + skp] = va_l;
            *(ushort8*)&Bsh[0][row * 32 + skp] = vb_h;
            *(ushort8*)&Bsh[1][row * 32 + skp] = vb_l;
        }
        __syncthreads();

        const int fr = lane & 15;
        const int fk = (lane >> 4) * 8;
        bf16x8 ah[4], al[4], bh[4], bl[4];
        #pragma unroll
        for (int i = 0; i < 4; ++i) {
            ah[i] = *(const bf16x8*)&Ash[0][(wm + i * 16 + fr) * 32 + fk];
            al[i] = *(const bf16x8*)&Ash[1][(wm + i * 16 + fr) * 32 + fk];
            bh[i] = *(const bf16x8*)&Bsh[0][(wn + i * 16 + fr) * 32 + fk];
            bl[i] = *(const bf16x8*)&Bsh[1][(wn + i * 16 + fr) * 32 + fk];
        }
        #pragma unroll
        for (int mi = 0; mi < 4; ++mi)
            #pragma unroll
            for (int ni = 0; ni < 4; ++ni) {
                acc[mi][ni] = __builtin_amdgcn_mfma_f32_16x16x32_bf16(ah[mi], bh[ni], acc[mi][ni], 0, 0, 0);
                acc[mi][ni] = __builtin_amdgcn_mfma_f32_16x16x32_bf16(ah[mi], bl[ni], acc[mi][ni], 0, 0, 0);
                acc[mi][ni] = __builtin_amdgcn_mfma_f32_16x16x32_bf16(al[mi], bh[ni], acc[mi][ni], 0, 0, 0);
            }
        __syncthreads();
    }

    const int fr = lane & 15;
    const int fq = (lane >> 4) * 4;
    #pragma unroll
    for (int mi = 0; mi < 4; ++mi) {
        #pragma unroll
        for (int ni = 0; ni < 4; ++ni) {
            int n = tn + wn + ni * 16 + fr;
            float bb = bias[n];
            #pragma unroll
            for (int r = 0; r < 4; ++r) {
                int m = tm + wm + mi * 16 + fq + r;
                if (m >= M) continue;
                float val = acc[mi][ni][r] + bb;
                if (MODE == 0) {
                    out0[(size_t)m * N + n] = val;
                } else {
                    int which = n / C_;
                    int rr = n - which * C_;
                    int h = rr >> 6, d = rr & 63;
                    float* dst = (which == 0) ? out0 : (which == 1) ? out1 : out2;
                    HL hl2 = split2(val);
                    ((unsigned int*)dst)[((size_t)h * N_ + m) * D_ + d] =
                        ((unsigned int)hl2.h << 16) | hl2.l;
                }
            }
        }
    }
}

// ---------------------------------------------------------------------------
// Spatial attention, split-K flash decode.
// Part A: grid (SPL, H_). Each block: 64-key chunk x all 20 q rows.
// Partials {o[20][64], m[20], l[20]} per (h, split).
// ---------------------------------------------------------------------------
__global__ __launch_bounds__(256)
void attn_spatial_part(const unsigned int* __restrict__ qp, const unsigned int* __restrict__ kp,
                       const unsigned int* __restrict__ vp, float* __restrict__ part)
{
    const int sp = blockIdx.x;   // 0..SPL-1
    const int h  = blockIdx.y;
    const int tid = threadIdx.x;
    const int n0 = sp * 64;

    __shared__ float qs[NS_][65];
    __shared__ float ks[64][65];
    __shared__ float vs[64][65];
    __shared__ float ps[NS_][65];
    __shared__ float red_m[NS_], red_l[NS_];

    for (int i = tid; i < NS_ * 64; i += 256) {
        int r = i >> 6, d = i & 63;
        qs[r][d] = unpk(qp[(((size_t)h * N_ + r) << 6) + d]);
    }
    for (int i = tid; i < 64 * 16; i += 256) {
        int j = i >> 4, dq = (i & 15) << 2;
        int n = n0 + j; if (n >= N_) n = N_ - 1;
        uint4v kv = *(const uint4v*)(kp + (((size_t)h * N_ + n) << 6) + dq);
        uint4v vv = *(const uint4v*)(vp + (((size_t)h * N_ + n) << 6) + dq);
        ks[j][dq + 0] = unpk(kv.x); ks[j][dq + 1] = unpk(kv.y);
        ks[j][dq + 2] = unpk(kv.z); ks[j][dq + 3] = unpk(kv.w);
        vs[j][dq + 0] = unpk(vv.x); vs[j][dq + 1] = unpk(vv.y);
        vs[j][dq + 2] = unpk(vv.z); vs[j][dq + 3] = unpk(vv.w);
    }
    __syncthreads();

    const int j = tid & 63;
    const int rg = tid >> 6;          // 0..3 -> rows rg*5 .. rg*5+4
    const bool jvalid = (n0 + j) < N_;

    // scores for 5 rows
    float sv[5];
    #pragma unroll
    for (int rr = 0; rr < 5; ++rr) {
        int r = rg * 5 + rr;
        float dot = 0.f;
        #pragma unroll 8
        for (int d = 0; d < 64; ++d) dot = fmaf(ks[j][d], qs[r][d], dot);
        sv[rr] = jvalid ? dot * 0.125f : -INFINITY;
    }
    // chunk softmax per row (reduce across 64 j-lanes of this wave)
    #pragma unroll
    for (int rr = 0; rr < 5; ++rr) {
        int r = rg * 5 + rr;
        float mm = sv[rr];
        #pragma unroll
        for (int off = 1; off < 64; off <<= 1) mm = fmaxf(mm, __shfl_xor(mm, off, 64));
        float p = __expf(sv[rr] - mm);
        ps[r][j] = p;
        float ls = p;
        #pragma unroll
        for (int off = 1; off < 64; off <<= 1) ls += __shfl_xor(ls, off, 64);
        if (j == 0) { red_m[r] = mm; red_l[r] = ls; }
    }
    __syncthreads();

    // partial PV: thread (d, rg) accumulates rows rg*5..+4
    const int d = tid & 63;
    float* po = part + ((size_t)(h * SPL + sp)) * (NS_ * 64);
    #pragma unroll
    for (int rr = 0; rr < 5; ++rr) {
        int r = rg * 5 + rr;
        float acc = 0.f;
        #pragma unroll 8
        for (int jj = 0; jj < 64; ++jj) acc = fmaf(ps[r][jj], vs[jj][d], acc);
        po[r * 64 + d] = acc;
    }
    if (tid < NS_) {
        float* pm = part + (size_t)H_ * SPL * NS_ * 64;
        float* pl = pm + (size_t)H_ * SPL * NS_;
        pm[(h * SPL + sp) * NS_ + tid] = red_m[tid];
        pl[(h * SPL + sp) * NS_ + tid] = red_l[tid];
    }
}

// Part B: combine SPL partials per (s, h) row. grid (NS_, H_), 64 threads.
__global__ __launch_bounds__(64)
void attn_spatial_comb(const float* __restrict__ part,
                       unsigned short* __restrict__ atthi, unsigned short* __restrict__ attlo)
{
    const int s = blockIdx.x, h = blockIdx.y;
    const int d = threadIdx.x;
    const float* pm = part + (size_t)H_ * SPL * NS_ * 64;
    const float* pl = pm + (size_t)H_ * SPL * NS_;

    float M = -INFINITY;
    #pragma unroll 2
    for (int sp = 0; sp < SPL; ++sp)
        M = fmaxf(M, pm[(h * SPL + sp) * NS_ + s]);
    float num = 0.f, den = 0.f;
    for (int sp = 0; sp < SPL; ++sp) {
        float w = __expf(pm[(h * SPL + sp) * NS_ + s] - M);
        den = fmaf(pl[(h * SPL + sp) * NS_ + s], w, den);
        num = fmaf(part[((size_t)(h * SPL + sp)) * (NS_ * 64) + s * 64 + d], w, num);
    }
    HL hl = split2(num / den);
    size_t idx = (size_t)s * C_ + h * 64 + d;
    atthi[idx] = hl.h;
    attlo[idx] = hl.l;
}

// ---------------------------------------------------------------------------
// Pano attention, MFMA flash-style (unchanged from round 5).
// ---------------------------------------------------------------------------
__global__ __launch_bounds__(256)
void attn_pano3(const unsigned int* __restrict__ qp, const unsigned int* __restrict__ kp,
                const unsigned int* __restrict__ vp,
                unsigned short* __restrict__ atthi, unsigned short* __restrict__ attlo)
{
    const int pt = blockIdx.x, vw = blockIdx.y, h = blockIdx.z;
    const int tid = threadIdx.x;
    const int lane = tid & 63;
    const int w = tid >> 6;
    const int p0 = pt * TPP;
    const int wr = w * 16;
    const int cv = (vw + 1) & 3;
    const int c = lane & 15;
    const int g = lane >> 4;

    __shared__ unsigned int Kl[64][68];
    __shared__ unsigned int VT[64][68];

    bf16x8 qh[2], ql[2];
    {
        int row = NS_ + vw * P_ + p0 + wr + c;
        if (row > N_ - 1) row = N_ - 1;
        const unsigned int* qrow = qp + (((size_t)h * N_ + row) << 6);
        #pragma unroll
        for (int ss = 0; ss < 2; ++ss) {
            uint4v u0 = *(const uint4v*)(qrow + ss * 32 + g * 8);
            uint4v u1 = *(const uint4v*)(qrow + ss * 32 + g * 8 + 4);
            unpack8(u0, u1, qh[ss], ql[ss]);
        }
    }

    float m[4], l[4];
    f32x4 o[4] = {};
    #pragma unroll
    for (int r = 0; r < 4; ++r) { m[r] = -INFINITY; l[r] = 0.f; }

    for (int ch = 0; ch < 9; ++ch) {
        #pragma unroll
        for (int i = 0; i < 4; ++i) {
            int f = i * 256 + tid;
            int key = f >> 4, dq = (f & 15) << 2;
            int n;
            if (ch < 7) {
                int sj = ch * 64 + key;
                n = (sj < NS_) ? sj : (NS_ + vw * P_ + (sj - NS_));
                if (sj >= NS_ + P_) n = 0;
            } else {
                int pp = p0 + (ch - 7) * 64 + key;
                if (pp >= P_) pp -= P_;
                if (pp >= P_) pp -= P_;
                n = NS_ + cv * P_ + pp;
            }
            uint4v kv = *(const uint4v*)(kp + (((size_t)h * N_ + n) << 6) + dq);
            *(uint4v*)&Kl[key][dq ^ (8 * (key & 3))] = kv;
        }
        {
            int kg = (tid & 15) << 2;
            int dq = (tid >> 4) << 2;
            uint4v rr[4];
            #pragma unroll
            for (int t = 0; t < 4; ++t) {
                int key = kg + t;
                int n;
                if (ch < 7) {
                    int sj = ch * 64 + key;
                    n = (sj < NS_) ? sj : (NS_ + vw * P_ + (sj - NS_));
                    if (sj >= NS_ + P_) n = 0;
                } else {
                    int pp = p0 + (ch - 7) * 64 + key;
                    if (pp >= P_) pp -= P_;
                    if (pp >= P_) pp -= P_;
                    n = NS_ + cv * P_ + pp;
                }
                rr[t] = *(const uint4v*)(vp + (((size_t)h * N_ + n) << 6) + dq);
            }
            #pragma unroll
            for (int j = 0; j < 4; ++j) {
                uint4v wv;
                wv.x = rr[0][j]; wv.y = rr[1][j]; wv.z = rr[2][j]; wv.w = rr[3][j];
                *(uint4v*)&VT[dq + j][kg ^ (8 * j)] = wv;
            }
        }
        __syncthreads();

        f32x4 s[4] = {};
        #pragma unroll
        for (int ss = 0; ss < 2; ++ss) {
            #pragma unroll
            for (int nf = 0; nf < 4; ++nf) {
                int key = nf * 16 + c;
                int db = (ss * 32 + g * 8) ^ (8 * (key & 3));
                uint4v u0 = *(const uint4v*)&Kl[key][db];
                uint4v u1 = *(const uint4v*)&Kl[key][db + 4];
                bf16x8 kh, klv;
                unpack8(u0, u1, kh, klv);
                s[nf] = __builtin_amdgcn_mfma_f32_16x16x32_bf16(qh[ss], kh,  s[nf], 0, 0, 0);
                s[nf] = __builtin_amdgcn_mfma_f32_16x16x32_bf16(qh[ss], klv, s[nf], 0, 0, 0);
                s[nf] = __builtin_amdgcn_mfma_f32_16x16x32_bf16(ql[ss], kh,  s[nf], 0, 0, 0);
            }
        }

        #pragma unroll
        for (int nf = 0; nf < 4; ++nf) {
            int col = nf * 16 + c;
            #pragma unroll
            for (int r = 0; r < 4; ++r) {
                int rowl = wr + g * 4 + r;
                bool valid;
                if (ch < 7) {
                    valid = (ch * 64 + col) < (NS_ + P_);
                } else {
                    int i = (ch - 7) * 64 + col;
                    valid = (i < 127) && ((unsigned)(i - rowl) < 64u);
                }
                s[nf][r] = valid ? s[nf][r] * 0.125f : -INFINITY;
            }
        }

        float fct[4];
        #pragma unroll
        for (int r = 0; r < 4; ++r) {
            float cm = fmaxf(fmaxf(s[0][r], s[1][r]), fmaxf(s[2][r], s[3][r]));
            cm = fmaxf(cm, __shfl_xor(cm, 1, 64));
            cm = fmaxf(cm, __shfl_xor(cm, 2, 64));
            cm = fmaxf(cm, __shfl_xor(cm, 4, 64));
            cm = fmaxf(cm, __shfl_xor(cm, 8, 64));
            float nm = fmaxf(m[r], cm);
            fct[r] = __expf(m[r] - nm);
            m[r] = nm;
        }

        __syncthreads();

        float ps[4] = {0.f, 0.f, 0.f, 0.f};
        #pragma unroll
        for (int nf = 0; nf < 4; ++nf) {
            #pragma unroll
            for (int r = 0; r < 4; ++r) {
                float p = __expf(s[nf][r] - m[r]);
                ps[r] += p;
                HL hl2 = split2(p);
                int rowl = wr + g * 4 + r;
                int col = (nf * 16 + c) ^ (8 * (rowl & 3));
                Kl[rowl][col] = ((unsigned int)hl2.h << 16) | hl2.l;
            }
        }
        #pragma unroll
        for (int r = 0; r < 4; ++r) {
            ps[r] += __shfl_xor(ps[r], 1, 64);
            ps[r] += __shfl_xor(ps[r], 2, 64);
            ps[r] += __shfl_xor(ps[r], 4, 64);
            ps[r] += __shfl_xor(ps[r], 8, 64);
            l[r] = l[r] * fct[r] + ps[r];
        }
        #pragma unroll
        for (int nf = 0; nf < 4; ++nf)
            #pragma unroll
            for (int r = 0; r < 4; ++r)
                o[nf][r] *= fct[r];

        bf16x8 pah[2], pal[2];
        {
            int prow = wr + c;
            int xw = 8 * (prow & 3);
            #pragma unroll
            for (int ss = 0; ss < 2; ++ss) {
                int kb = (ss * 32 + g * 8) ^ xw;
                uint4v u0 = *(const uint4v*)&Kl[prow][kb];
                uint4v u1 = *(const uint4v*)&Kl[prow][kb + 4];
                unpack8(u0, u1, pah[ss], pal[ss]);
            }
        }

        int xv = 8 * (c & 3);
        #pragma unroll
        for (int ss = 0; ss < 2; ++ss) {
            #pragma unroll
            for (int nf = 0; nf < 4; ++nf) {
                int d = nf * 16 + c;
                int kb = (ss * 32 + g * 8) ^ xv;
                uint4v u0 = *(const uint4v*)&VT[d][kb];
                uint4v u1 = *(const uint4v*)&VT[d][kb + 4];
                bf16x8 vh, vl;
                unpack8(u0, u1, vh, vl);
                o[nf] = __builtin_amdgcn_mfma_f32_16x16x32_bf16(pah[ss], vh, o[nf], 0, 0, 0);
                o[nf] = __builtin_amdgcn_mfma_f32_16x16x32_bf16(pah[ss], vl, o[nf], 0, 0, 0);
                o[nf] = __builtin_amdgcn_mfma_f32_16x16x32_bf16(pal[ss], vh, o[nf], 0, 0, 0);
            }
        }
        __syncthreads();
    }

    #pragma unroll
    for (int r = 0; r < 4; ++r) {
        int rowl = wr + g * 4 + r;
        int prow = p0 + rowl;
        if (prow >= P_) continue;
        float inv = 1.0f / l[r];
        size_t base = ((size_t)(NS_ + vw * P_ + prow)) * C_ + h * 64 + c;
        #pragma unroll
        for (int nf = 0; nf < 4; ++nf) {
            HL hl2 = split2(o[nf][r] * inv);
            atthi[base + nf * 16] = hl2.h;
            attlo[base + nf * 16] = hl2.l;
        }
    }
}

// ---------------------------------------------------------------------------
extern "C" void kernel_launch(void* const* d_in, const int* in_sizes, int n_in,
                              void* d_out, int out_size, void* d_ws, size_t ws_size,
                              hipStream_t stream)
{
    const float* x       = (const float*)d_in[0];
    const float* qkv_w   = (const float*)d_in[1];
    const float* qkv_b   = (const float*)d_in[2];
    const float* proj_w  = (const float*)d_in[3];
    const float* proj_b  = (const float*)d_in[4];
    float* out = (float*)d_out;

    const size_t per = (size_t)H_ * N_ * D_;
    unsigned int* qp = (unsigned int*)d_ws;
    unsigned int* kp = qp + per;
    unsigned int* vp = kp + per;
    unsigned short* xhi  = (unsigned short*)(vp + per);
    unsigned short* xlo  = xhi + (size_t)N_ * C_;
    unsigned short* whi  = xlo + (size_t)N_ * C_;
    unsigned short* wlo  = whi + (size_t)3 * C_ * C_;
    unsigned short* pwhi = wlo + (size_t)3 * C_ * C_;
    unsigned short* pwlo = pwhi + (size_t)C_ * C_;
    unsigned short* atthi = pwlo + (size_t)C_ * C_;
    unsigned short* attlo = atthi + (size_t)N_ * C_;
    float* spart = (float*)(attlo + (size_t)N_ * C_);
    // spart: o [H_][SPL][20][64] + m [H_][SPL][20] + l [H_][SPL][20]

    // 0) split inputs to bf16 hi/lo (single kernel)
    {
        int total = N4_X + N4_W + N4_PW;
        split_all<<<(total + 255) / 256, 256, 0, stream>>>(x, qkv_w, proj_w,
                                                           xhi, xlo, whi, wlo, pwhi, pwlo);
    }

    // 1) QKV projection (MFMA), packed-u32 scatter into q/k/v [h][n][d]
    dim3 g1((N_ + 127) / 128, (3 * C_) / 128);
    gemm_mfma<1><<<g1, 256, 0, stream>>>(xhi, xlo, whi, wlo, qkv_b, N_, 3 * C_,
                                         (float*)qp, (float*)kp, (float*)vp);

    // 2) spatial attention: split-K partials + combine
    attn_spatial_part<<<dim3(SPL, H_), 256, 0, stream>>>(qp, kp, vp, spart);
    attn_spatial_comb<<<dim3(NS_, H_), 64, 0, stream>>>(spart, atthi, attlo);

    // 3) panoramic attention rows (MFMA flash)
    attn_pano3<<<dim3(PTILES, V_, H_), 256, 0, stream>>>(qp, kp, vp, atthi, attlo);

    // 4) output projection (MFMA)
    dim3 g2((N_ + 127) / 128, C_ / 128);
    gemm_mfma<0><<<g2, 256, 0, stream>>>(atthi, attlo, pwhi, pwlo, proj_b, N_, C_, out, nullptr, nullptr);
}

// Round 8
// 162.686 us; speedup vs baseline: 4.9908x; 1.0194x over previous
//
#include <hip/hip_runtime.h>
#include <hip/hip_bf16.h>
#include <math.h>

#define H_  12
#define N_  1620
#define D_  64
#define C_  768
#define NS_ 20
#define V_  4
#define P_  400

#define TPP    64
#define PTILES 7    // ceil(400/64)
#define SPL    26   // spatial key splits of 64 (26*64 = 1664 >= 1620)

typedef __bf16 bf16x8 __attribute__((ext_vector_type(8)));
typedef float f32x4 __attribute__((ext_vector_type(4)));
typedef unsigned short ushort8 __attribute__((ext_vector_type(8)));
typedef unsigned short ushort4v __attribute__((ext_vector_type(4)));
typedef unsigned int uint4v __attribute__((ext_vector_type(4)));

struct HL { unsigned short h, l; };

__device__ __forceinline__ unsigned short bf16_rne(float v) {
    unsigned int u = __builtin_bit_cast(unsigned int, v);
    return (unsigned short)((u + 0x7fffu + ((u >> 16) & 1u)) >> 16);
}
__device__ __forceinline__ HL split2(float v) {
    HL r;
    r.h = bf16_rne(v);
    float hf = __builtin_bit_cast(float, (unsigned int)r.h << 16);
    r.l = bf16_rne(v - hf);
    return r;
}
__device__ __forceinline__ float unpk(unsigned int u) {
    return __builtin_bit_cast(float, u & 0xffff0000u) + __builtin_bit_cast(float, u << 16);
}
__device__ __forceinline__ void unpack8(uint4v a, uint4v b, bf16x8& hi, bf16x8& lo) {
    ushort8 ea = __builtin_bit_cast(ushort8, a);
    ushort8 eb = __builtin_bit_cast(ushort8, b);
    hi = __builtin_bit_cast(bf16x8, __builtin_shufflevector(ea, eb, 1,3,5,7,9,11,13,15));
    lo = __builtin_bit_cast(bf16x8, __builtin_shufflevector(ea, eb, 0,2,4,6,8,10,12,14));
}

// ---------------------------------------------------------------------------
// One fused split kernel for x, qkv_w, proj_w.
// ---------------------------------------------------------------------------
#define N4_X  ((N_ * C_) / 4)
#define N4_W  ((3 * C_ * C_) / 4)
#define N4_PW ((C_ * C_) / 4)

__global__ __launch_bounds__(256)
void split_all(const float* __restrict__ x, const float* __restrict__ w,
               const float* __restrict__ pw,
               unsigned short* __restrict__ xhi, unsigned short* __restrict__ xlo,
               unsigned short* __restrict__ whi, unsigned short* __restrict__ wlo,
               unsigned short* __restrict__ pwhi, unsigned short* __restrict__ pwlo)
{
    int i = blockIdx.x * 256 + threadIdx.x;
    const float* src; unsigned short* dh; unsigned short* dl; int idx;
    if (i < N4_X)                { src = x;  dh = xhi;  dl = xlo;  idx = i; }
    else if (i < N4_X + N4_W)    { src = w;  dh = whi;  dl = wlo;  idx = i - N4_X; }
    else if (i < N4_X + N4_W + N4_PW) { src = pw; dh = pwhi; dl = pwlo; idx = i - N4_X - N4_W; }
    else return;
    float4 v = ((const float4*)src)[idx];
    HL a = split2(v.x), b = split2(v.y), c = split2(v.z), d = split2(v.w);
    ushort4v h, l;
    h.x = a.h; h.y = b.h; h.z = c.h; h.w = d.h;
    l.x = a.l; l.y = b.l; l.z = c.l; l.w = d.l;
    ((ushort4v*)dh)[idx] = h;
    ((ushort4v*)dl)[idx] = l;
}

// ---------------------------------------------------------------------------
// MFMA NT GEMM with split-2 bf16 inputs. C = A * B^T + bias.
// MODE 0: out0 row-major MxN (f32).
// MODE 1: QKV scatter; writes PACKED u32 (hi<<16|lo) into q/k/v [h][N_][D_].
// ---------------------------------------------------------------------------
template<int MODE>
__global__ __launch_bounds__(256)
void gemm_mfma(const unsigned short* __restrict__ Ah, const unsigned short* __restrict__ Al,
               const unsigned short* __restrict__ Bh, const unsigned short* __restrict__ Bl,
               const float* __restrict__ bias, int M, int N,
               float* __restrict__ out0, float* __restrict__ out1, float* __restrict__ out2)
{
    __shared__ unsigned short Ash[2][128 * 32];
    __shared__ unsigned short Bsh[2][128 * 32];
    const int tid = threadIdx.x;
    const int tm = blockIdx.x * 128;
    const int tn = blockIdx.y * 128;
    const int lane = tid & 63;
    const int w = tid >> 6;
    const int wm = (w >> 1) * 64;
    const int wn = (w & 1) * 64;

    f32x4 acc[4][4] = {};

    const int srow = tid >> 2;
    const int skp  = (tid & 3) * 8;

    for (int k0 = 0; k0 < 768; k0 += 32) {
        #pragma unroll
        for (int half = 0; half < 2; ++half) {
            int row = srow + half * 64;
            int gmA = tm + row; if (gmA > M - 1) gmA = M - 1;
            int gnB = tn + row;
            ushort8 va_h = *(const ushort8*)(Ah + (size_t)gmA * 768 + k0 + skp);
            ushort8 va_l = *(const ushort8*)(Al + (size_t)gmA * 768 + k0 + skp);
            ushort8 vb_h = *(const ushort8*)(Bh + (size_t)gnB * 768 + k0 + skp);
            ushort8 vb_l = *(const ushort8*)(Bl + (size_t)gnB * 768 + k0 + skp);
            *(ushort8*)&Ash[0][row * 32 + skp] = va_h;
            *(ushort8*)&Ash[1][row * 32 + skp] = va_l;
            *(ushort8*)&Bsh[0][row * 32 + skp] = vb_h;
            *(ushort8*)&Bsh[1][row * 32 + skp] = vb_l;
        }
        __syncthreads();

        const int fr = lane & 15;
        const int fk = (lane >> 4) * 8;
        bf16x8 ah[4], al[4], bh[4], bl[4];
        #pragma unroll
        for (int i = 0; i < 4; ++i) {
            ah[i] = *(const bf16x8*)&Ash[0][(wm + i * 16 + fr) * 32 + fk];
            al[i] = *(const bf16x8*)&Ash[1][(wm + i * 16 + fr) * 32 + fk];
            bh[i] = *(const bf16x8*)&Bsh[0][(wn + i * 16 + fr) * 32 + fk];
            bl[i] = *(const bf16x8*)&Bsh[1][(wn + i * 16 + fr) * 32 + fk];
        }
        #pragma unroll
        for (int mi = 0; mi < 4; ++mi)
            #pragma unroll
            for (int ni = 0; ni < 4; ++ni) {
                acc[mi][ni] = __builtin_amdgcn_mfma_f32_16x16x32_bf16(ah[mi], bh[ni], acc[mi][ni], 0, 0, 0);
                acc[mi][ni] = __builtin_amdgcn_mfma_f32_16x16x32_bf16(ah[mi], bl[ni], acc[mi][ni], 0, 0, 0);
                acc[mi][ni] = __builtin_amdgcn_mfma_f32_16x16x32_bf16(al[mi], bh[ni], acc[mi][ni], 0, 0, 0);
            }
        __syncthreads();
    }

    const int fr = lane & 15;
    const int fq = (lane >> 4) * 4;
    #pragma unroll
    for (int mi = 0; mi < 4; ++mi) {
        #pragma unroll
        for (int ni = 0; ni < 4; ++ni) {
            int n = tn + wn + ni * 16 + fr;
            float bb = bias[n];
            #pragma unroll
            for (int r = 0; r < 4; ++r) {
                int m = tm + wm + mi * 16 + fq + r;
                if (m >= M) continue;
                float val = acc[mi][ni][r] + bb;
                if (MODE == 0) {
                    out0[(size_t)m * N + n] = val;
                } else {
                    int which = n / C_;
                    int rr = n - which * C_;
                    int h = rr >> 6, d = rr & 63;
                    float* dst = (which == 0) ? out0 : (which == 1) ? out1 : out2;
                    HL hl2 = split2(val);
                    ((unsigned int*)dst)[((size_t)h * N_ + m) * D_ + d] =
                        ((unsigned int)hl2.h << 16) | hl2.l;
                }
            }
        }
    }
}

// ---------------------------------------------------------------------------
// Spatial attention, split-K flash decode.
// ---------------------------------------------------------------------------
__global__ __launch_bounds__(256)
void attn_spatial_part(const unsigned int* __restrict__ qp, const unsigned int* __restrict__ kp,
                       const unsigned int* __restrict__ vp, float* __restrict__ part)
{
    const int sp = blockIdx.x;
    const int h  = blockIdx.y;
    const int tid = threadIdx.x;
    const int n0 = sp * 64;

    __shared__ float qs[NS_][65];
    __shared__ float ks[64][65];
    __shared__ float vs[64][65];
    __shared__ float ps[NS_][65];
    __shared__ float red_m[NS_], red_l[NS_];

    for (int i = tid; i < NS_ * 64; i += 256) {
        int r = i >> 6, d = i & 63;
        qs[r][d] = unpk(qp[(((size_t)h * N_ + r) << 6) + d]);
    }
    for (int i = tid; i < 64 * 16; i += 256) {
        int j = i >> 4, dq = (i & 15) << 2;
        int n = n0 + j; if (n >= N_) n = N_ - 1;
        uint4v kv = *(const uint4v*)(kp + (((size_t)h * N_ + n) << 6) + dq);
        uint4v vv = *(const uint4v*)(vp + (((size_t)h * N_ + n) << 6) + dq);
        ks[j][dq + 0] = unpk(kv.x); ks[j][dq + 1] = unpk(kv.y);
        ks[j][dq + 2] = unpk(kv.z); ks[j][dq + 3] = unpk(kv.w);
        vs[j][dq + 0] = unpk(vv.x); vs[j][dq + 1] = unpk(vv.y);
        vs[j][dq + 2] = unpk(vv.z); vs[j][dq + 3] = unpk(vv.w);
    }
    __syncthreads();

    const int j = tid & 63;
    const int rg = tid >> 6;
    const bool jvalid = (n0 + j) < N_;

    float sv[5];
    #pragma unroll
    for (int rr = 0; rr < 5; ++rr) {
        int r = rg * 5 + rr;
        float dot = 0.f;
        #pragma unroll 8
        for (int d = 0; d < 64; ++d) dot = fmaf(ks[j][d], qs[r][d], dot);
        sv[rr] = jvalid ? dot * 0.125f : -INFINITY;
    }
    #pragma unroll
    for (int rr = 0; rr < 5; ++rr) {
        int r = rg * 5 + rr;
        float mm = sv[rr];
        #pragma unroll
        for (int off = 1; off < 64; off <<= 1) mm = fmaxf(mm, __shfl_xor(mm, off, 64));
        float p = __expf(sv[rr] - mm);
        ps[r][j] = p;
        float ls = p;
        #pragma unroll
        for (int off = 1; off < 64; off <<= 1) ls += __shfl_xor(ls, off, 64);
        if (j == 0) { red_m[r] = mm; red_l[r] = ls; }
    }
    __syncthreads();

    const int d = tid & 63;
    float* po = part + ((size_t)(h * SPL + sp)) * (NS_ * 64);
    #pragma unroll
    for (int rr = 0; rr < 5; ++rr) {
        int r = rg * 5 + rr;
        float acc = 0.f;
        #pragma unroll 8
        for (int jj = 0; jj < 64; ++jj) acc = fmaf(ps[r][jj], vs[jj][d], acc);
        po[r * 64 + d] = acc;
    }
    if (tid < NS_) {
        float* pm = part + (size_t)H_ * SPL * NS_ * 64;
        float* pl = pm + (size_t)H_ * SPL * NS_;
        pm[(h * SPL + sp) * NS_ + tid] = red_m[tid];
        pl[(h * SPL + sp) * NS_ + tid] = red_l[tid];
    }
}

__global__ __launch_bounds__(64)
void attn_spatial_comb(const float* __restrict__ part,
                       unsigned short* __restrict__ atthi, unsigned short* __restrict__ attlo)
{
    const int s = blockIdx.x, h = blockIdx.y;
    const int d = threadIdx.x;
    const float* pm = part + (size_t)H_ * SPL * NS_ * 64;
    const float* pl = pm + (size_t)H_ * SPL * NS_;

    float M = -INFINITY;
    #pragma unroll 2
    for (int sp = 0; sp < SPL; ++sp)
        M = fmaxf(M, pm[(h * SPL + sp) * NS_ + s]);
    float num = 0.f, den = 0.f;
    for (int sp = 0; sp < SPL; ++sp) {
        float w = __expf(pm[(h * SPL + sp) * NS_ + s] - M);
        den = fmaf(pl[(h * SPL + sp) * NS_ + s], w, den);
        num = fmaf(part[((size_t)(h * SPL + sp)) * (NS_ * 64) + s * 64 + d], w, num);
    }
    HL hl = split2(num / den);
    size_t idx = (size_t)s * C_ + h * 64 + d;
    atthi[idx] = hl.h;
    attlo[idx] = hl.l;
}

// ---------------------------------------------------------------------------
// Pano attention, MFMA flash-style. 1-D grid of 336 with bijective
// XCD-chunked swizzle: the 7 pt-tiles sharing one (h,vw) K/V panel land on
// the same XCD -> panel refetches become L2 hits.
// ---------------------------------------------------------------------------
__global__ __launch_bounds__(256)
void attn_pano3(const unsigned int* __restrict__ qp, const unsigned int* __restrict__ kp,
                const unsigned int* __restrict__ vp,
                unsigned short* __restrict__ atthi, unsigned short* __restrict__ attlo)
{
    // 336 blocks = 8 XCDs x 42; orig%8 = XCD (round-robin dispatch)
    const int orig = blockIdx.x;
    const int swz = (orig & 7) * 42 + (orig >> 3);
    const int pt = swz % PTILES;
    const int t2 = swz / PTILES;
    const int vw = t2 & 3;
    const int h  = t2 >> 2;

    const int tid = threadIdx.x;
    const int lane = tid & 63;
    const int w = tid >> 6;
    const int p0 = pt * TPP;
    const int wr = w * 16;
    const int cv = (vw + 1) & 3;
    const int c = lane & 15;
    const int g = lane >> 4;

    __shared__ unsigned int Kl[64][68];
    __shared__ unsigned int VT[64][68];

    bf16x8 qh[2], ql[2];
    {
        int row = NS_ + vw * P_ + p0 + wr + c;
        if (row > N_ - 1) row = N_ - 1;
        const unsigned int* qrow = qp + (((size_t)h * N_ + row) << 6);
        #pragma unroll
        for (int ss = 0; ss < 2; ++ss) {
            uint4v u0 = *(const uint4v*)(qrow + ss * 32 + g * 8);
            uint4v u1 = *(const uint4v*)(qrow + ss * 32 + g * 8 + 4);
            unpack8(u0, u1, qh[ss], ql[ss]);
        }
    }

    float m[4], l[4];
    f32x4 o[4] = {};
    #pragma unroll
    for (int r = 0; r < 4; ++r) { m[r] = -INFINITY; l[r] = 0.f; }

    for (int ch = 0; ch < 9; ++ch) {
        #pragma unroll
        for (int i = 0; i < 4; ++i) {
            int f = i * 256 + tid;
            int key = f >> 4, dq = (f & 15) << 2;
            int n;
            if (ch < 7) {
                int sj = ch * 64 + key;
                n = (sj < NS_) ? sj : (NS_ + vw * P_ + (sj - NS_));
                if (sj >= NS_ + P_) n = 0;
            } else {
                int pp = p0 + (ch - 7) * 64 + key;
                if (pp >= P_) pp -= P_;
                if (pp >= P_) pp -= P_;
                n = NS_ + cv * P_ + pp;
            }
            uint4v kv = *(const uint4v*)(kp + (((size_t)h * N_ + n) << 6) + dq);
            *(uint4v*)&Kl[key][dq ^ (8 * (key & 3))] = kv;
        }
        {
            int kg = (tid & 15) << 2;
            int dq = (tid >> 4) << 2;
            uint4v rr[4];
            #pragma unroll
            for (int t = 0; t < 4; ++t) {
                int key = kg + t;
                int n;
                if (ch < 7) {
                    int sj = ch * 64 + key;
                    n = (sj < NS_) ? sj : (NS_ + vw * P_ + (sj - NS_));
                    if (sj >= NS_ + P_) n = 0;
                } else {
                    int pp = p0 + (ch - 7) * 64 + key;
                    if (pp >= P_) pp -= P_;
                    if (pp >= P_) pp -= P_;
                    n = NS_ + cv * P_ + pp;
                }
                rr[t] = *(const uint4v*)(vp + (((size_t)h * N_ + n) << 6) + dq);
            }
            #pragma unroll
            for (int j = 0; j < 4; ++j) {
                uint4v wv;
                wv.x = rr[0][j]; wv.y = rr[1][j]; wv.z = rr[2][j]; wv.w = rr[3][j];
                *(uint4v*)&VT[dq + j][kg ^ (8 * j)] = wv;
            }
        }
        __syncthreads();

        f32x4 s[4] = {};
        #pragma unroll
        for (int ss = 0; ss < 2; ++ss) {
            #pragma unroll
            for (int nf = 0; nf < 4; ++nf) {
                int key = nf * 16 + c;
                int db = (ss * 32 + g * 8) ^ (8 * (key & 3));
                uint4v u0 = *(const uint4v*)&Kl[key][db];
                uint4v u1 = *(const uint4v*)&Kl[key][db + 4];
                bf16x8 kh, klv;
                unpack8(u0, u1, kh, klv);
                s[nf] = __builtin_amdgcn_mfma_f32_16x16x32_bf16(qh[ss], kh,  s[nf], 0, 0, 0);
                s[nf] = __builtin_amdgcn_mfma_f32_16x16x32_bf16(qh[ss], klv, s[nf], 0, 0, 0);
                s[nf] = __builtin_amdgcn_mfma_f32_16x16x32_bf16(ql[ss], kh,  s[nf], 0, 0, 0);
            }
        }

        #pragma unroll
        for (int nf = 0; nf < 4; ++nf) {
            int col = nf * 16 + c;
            #pragma unroll
            for (int r = 0; r < 4; ++r) {
                int rowl = wr + g * 4 + r;
                bool valid;
                if (ch < 7) {
                    valid = (ch * 64 + col) < (NS_ + P_);
                } else {
                    int i = (ch - 7) * 64 + col;
                    valid = (i < 127) && ((unsigned)(i - rowl) < 64u);
                }
                s[nf][r] = valid ? s[nf][r] * 0.125f : -INFINITY;
            }
        }

        float fct[4];
        #pragma unroll
        for (int r = 0; r < 4; ++r) {
            float cm = fmaxf(fmaxf(s[0][r], s[1][r]), fmaxf(s[2][r], s[3][r]));
            cm = fmaxf(cm, __shfl_xor(cm, 1, 64));
            cm = fmaxf(cm, __shfl_xor(cm, 2, 64));
            cm = fmaxf(cm, __shfl_xor(cm, 4, 64));
            cm = fmaxf(cm, __shfl_xor(cm, 8, 64));
            float nm = fmaxf(m[r], cm);
            fct[r] = __expf(m[r] - nm);
            m[r] = nm;
        }

        __syncthreads();

        float ps[4] = {0.f, 0.f, 0.f, 0.f};
        #pragma unroll
        for (int nf = 0; nf < 4; ++nf) {
            #pragma unroll
            for (int r = 0; r < 4; ++r) {
                float p = __expf(s[nf][r] - m[r]);
                ps[r] += p;
                HL hl2 = split2(p);
                int rowl = wr + g * 4 + r;
                int col = (nf * 16 + c) ^ (8 * (rowl & 3));
                Kl[rowl][col] = ((unsigned int)hl2.h << 16) | hl2.l;
            }
        }
        #pragma unroll
        for (int r = 0; r < 4; ++r) {
            ps[r] += __shfl_xor(ps[r], 1, 64);
            ps[r] += __shfl_xor(ps[r], 2, 64);
            ps[r] += __shfl_xor(ps[r], 4, 64);
            ps[r] += __shfl_xor(ps[r], 8, 64);
            l[r] = l[r] * fct[r] + ps[r];
        }
        #pragma unroll
        for (int nf = 0; nf < 4; ++nf)
            #pragma unroll
            for (int r = 0; r < 4; ++r)
                o[nf][r] *= fct[r];

        bf16x8 pah[2], pal[2];
        {
            int prow = wr + c;
            int xw = 8 * (prow & 3);
            #pragma unroll
            for (int ss = 0; ss < 2; ++ss) {
                int kb = (ss * 32 + g * 8) ^ xw;
                uint4v u0 = *(const uint4v*)&Kl[prow][kb];
                uint4v u1 = *(const uint4v*)&Kl[prow][kb + 4];
                unpack8(u0, u1, pah[ss], pal[ss]);
            }
        }

        int xv = 8 * (c & 3);
        #pragma unroll
        for (int ss = 0; ss < 2; ++ss) {
            #pragma unroll
            for (int nf = 0; nf < 4; ++nf) {
                int d = nf * 16 + c;
                int kb = (ss * 32 + g * 8) ^ xv;
                uint4v u0 = *(const uint4v*)&VT[d][kb];
                uint4v u1 = *(const uint4v*)&VT[d][kb + 4];
                bf16x8 vh, vl;
                unpack8(u0, u1, vh, vl);
                o[nf] = __builtin_amdgcn_mfma_f32_16x16x32_bf16(pah[ss], vh, o[nf], 0, 0, 0);
                o[nf] = __builtin_amdgcn_mfma_f32_16x16x32_bf16(pah[ss], vl, o[nf], 0, 0, 0);
                o[nf] = __builtin_amdgcn_mfma_f32_16x16x32_bf16(pal[ss], vh, o[nf], 0, 0, 0);
            }
        }
        __syncthreads();
    }

    #pragma unroll
    for (int r = 0; r < 4; ++r) {
        int rowl = wr + g * 4 + r;
        int prow = p0 + rowl;
        if (prow >= P_) continue;
        float inv = 1.0f / l[r];
        size_t base = ((size_t)(NS_ + vw * P_ + prow)) * C_ + h * 64 + c;
        #pragma unroll
        for (int nf = 0; nf < 4; ++nf) {
            HL hl2 = split2(o[nf][r] * inv);
            atthi[base + nf * 16] = hl2.h;
            attlo[base + nf * 16] = hl2.l;
        }
    }
}

// ---------------------------------------------------------------------------
extern "C" void kernel_launch(void* const* d_in, const int* in_sizes, int n_in,
                              void* d_out, int out_size, void* d_ws, size_t ws_size,
                              hipStream_t stream)
{
    const float* x       = (const float*)d_in[0];
    const float* qkv_w   = (const float*)d_in[1];
    const float* qkv_b   = (const float*)d_in[2];
    const float* proj_w  = (const float*)d_in[3];
    const float* proj_b  = (const float*)d_in[4];
    float* out = (float*)d_out;

    const size_t per = (size_t)H_ * N_ * D_;
    unsigned int* qp = (unsigned int*)d_ws;
    unsigned int* kp = qp + per;
    unsigned int* vp = kp + per;
    unsigned short* xhi  = (unsigned short*)(vp + per);
    unsigned short* xlo  = xhi + (size_t)N_ * C_;
    unsigned short* whi  = xlo + (size_t)N_ * C_;
    unsigned short* wlo  = whi + (size_t)3 * C_ * C_;
    unsigned short* pwhi = wlo + (size_t)3 * C_ * C_;
    unsigned short* pwlo = pwhi + (size_t)C_ * C_;
    unsigned short* atthi = pwlo + (size_t)C_ * C_;
    unsigned short* attlo = atthi + (size_t)N_ * C_;
    float* spart = (float*)(attlo + (size_t)N_ * C_);

    // 0) split inputs to bf16 hi/lo (single kernel)
    {
        int total = N4_X + N4_W + N4_PW;
        split_all<<<(total + 255) / 256, 256, 0, stream>>>(x, qkv_w, proj_w,
                                                           xhi, xlo, whi, wlo, pwhi, pwlo);
    }

    // 1) QKV projection (MFMA), packed-u32 scatter into q/k/v [h][n][d]
    dim3 g1((N_ + 127) / 128, (3 * C_) / 128);
    gemm_mfma<1><<<g1, 256, 0, stream>>>(xhi, xlo, whi, wlo, qkv_b, N_, 3 * C_,
                                         (float*)qp, (float*)kp, (float*)vp);

    // 2) spatial attention: split-K partials + combine
    attn_spatial_part<<<dim3(SPL, H_), 256, 0, stream>>>(qp, kp, vp, spart);
    attn_spatial_comb<<<dim3(NS_, H_), 64, 0, stream>>>(spart, atthi, attlo);

    // 3) panoramic attention rows (MFMA flash, XCD-swizzled 1-D grid)
    attn_pano3<<<PTILES * V_ * H_, 256, 0, stream>>>(qp, kp, vp, atthi, attlo);

    // 4) output projection (MFMA)
    dim3 g2((N_ + 127) / 128, C_ / 128);
    gemm_mfma<0><<<g2, 256, 0, stream>>>(atthi, attlo, pwhi, pwlo, proj_b, N_, C_, out, nullptr, nullptr);
}

// Round 9
// 136.231 us; speedup vs baseline: 5.9599x; 1.1942x over previous
//
#include <hip/hip_runtime.h>
#include <hip/hip_bf16.h>
#include <math.h>

#define H_  12
#define N_  1620
#define D_  64
#define C_  768
#define NS_ 20
#define V_  4
#define P_  400

#define TPP    64
#define PTILES 7    // ceil(400/64)
#define SPL    26   // spatial key splits of 64

typedef __bf16 bf16x8 __attribute__((ext_vector_type(8)));
typedef float f32x4 __attribute__((ext_vector_type(4)));
typedef unsigned short ushort8 __attribute__((ext_vector_type(8)));
typedef unsigned short ushort4v __attribute__((ext_vector_type(4)));
typedef unsigned int uint4v __attribute__((ext_vector_type(4)));

struct HL { unsigned short h, l; };

__device__ __forceinline__ unsigned short bf16_rne(float v) {
    unsigned int u = __builtin_bit_cast(unsigned int, v);
    return (unsigned short)((u + 0x7fffu + ((u >> 16) & 1u)) >> 16);
}
__device__ __forceinline__ HL split2(float v) {
    HL r;
    r.h = bf16_rne(v);
    float hf = __builtin_bit_cast(float, (unsigned int)r.h << 16);
    r.l = bf16_rne(v - hf);
    return r;
}
__device__ __forceinline__ float unpk(unsigned int u) {
    return __builtin_bit_cast(float, u & 0xffff0000u) + __builtin_bit_cast(float, u << 16);
}
__device__ __forceinline__ void unpack8(uint4v a, uint4v b, bf16x8& hi, bf16x8& lo) {
    ushort8 ea = __builtin_bit_cast(ushort8, a);
    ushort8 eb = __builtin_bit_cast(ushort8, b);
    hi = __builtin_bit_cast(bf16x8, __builtin_shufflevector(ea, eb, 1,3,5,7,9,11,13,15));
    lo = __builtin_bit_cast(bf16x8, __builtin_shufflevector(ea, eb, 0,2,4,6,8,10,12,14));
}
// bijective XCD-chunked swizzle (m204): consecutive outputs land on one XCD
__device__ __forceinline__ int xcd_swz(int orig, int nwg) {
    int q = nwg >> 3, r = nwg & 7;
    int x = orig & 7, p = orig >> 3;
    return (x < r ? x * (q + 1) : r * (q + 1) + (x - r) * q) + p;
}

// ---------------------------------------------------------------------------
// One fused split kernel for x, qkv_w, proj_w.
// ---------------------------------------------------------------------------
#define N4_X  ((N_ * C_) / 4)
#define N4_W  ((3 * C_ * C_) / 4)
#define N4_PW ((C_ * C_) / 4)

__global__ __launch_bounds__(256)
void split_all(const float* __restrict__ x, const float* __restrict__ w,
               const float* __restrict__ pw,
               unsigned short* __restrict__ xhi, unsigned short* __restrict__ xlo,
               unsigned short* __restrict__ whi, unsigned short* __restrict__ wlo,
               unsigned short* __restrict__ pwhi, unsigned short* __restrict__ pwlo)
{
    int i = blockIdx.x * 256 + threadIdx.x;
    const float* src; unsigned short* dh; unsigned short* dl; int idx;
    if (i < N4_X)                { src = x;  dh = xhi;  dl = xlo;  idx = i; }
    else if (i < N4_X + N4_W)    { src = w;  dh = whi;  dl = wlo;  idx = i - N4_X; }
    else if (i < N4_X + N4_W + N4_PW) { src = pw; dh = pwhi; dl = pwlo; idx = i - N4_X - N4_W; }
    else return;
    float4 v = ((const float4*)src)[idx];
    HL a = split2(v.x), b = split2(v.y), c = split2(v.z), d = split2(v.w);
    ushort4v h, l;
    h.x = a.h; h.y = b.h; h.z = c.h; h.w = d.h;
    l.x = a.l; l.y = b.l; l.z = c.l; l.w = d.l;
    ((ushort4v*)dh)[idx] = h;
    ((ushort4v*)dl)[idx] = l;
}

// ---------------------------------------------------------------------------
// MFMA NT GEMM, split-2 bf16. Tile 128(M) x 64(N), BK=32, 4 waves (2x2).
// 1-D grid with XCD swizzle. MODE 0: f32 out. MODE 1: QKV packed-u32 scatter.
// ---------------------------------------------------------------------------
template<int MODE>
__global__ __launch_bounds__(256)
void gemm_mfma(const unsigned short* __restrict__ Ah, const unsigned short* __restrict__ Al,
               const unsigned short* __restrict__ Bh, const unsigned short* __restrict__ Bl,
               const float* __restrict__ bias, int M, int N,
               float* __restrict__ out0, float* __restrict__ out1, float* __restrict__ out2)
{
    __shared__ unsigned short Ash[2][128 * 32];
    __shared__ unsigned short Bsh[2][64 * 32];
    const int tid = threadIdx.x;

    const int wg = xcd_swz(blockIdx.x, gridDim.x);
    const int tmc = (M + 127) >> 7;
    const int tm = (wg % tmc) * 128;
    const int tn = (wg / tmc) * 64;

    const int lane = tid & 63;
    const int w = tid >> 6;
    const int wm = (w >> 1) * 64;
    const int wn = (w & 1) * 32;

    f32x4 acc[4][2] = {};

    const int srow = tid >> 2;          // 0..63
    const int skp  = (tid & 3) * 8;

    for (int k0 = 0; k0 < 768; k0 += 32) {
        #pragma unroll
        for (int half = 0; half < 2; ++half) {
            int row = srow + half * 64;
            int gmA = tm + row; if (gmA > M - 1) gmA = M - 1;
            ushort8 va_h = *(const ushort8*)(Ah + (size_t)gmA * 768 + k0 + skp);
            ushort8 va_l = *(const ushort8*)(Al + (size_t)gmA * 768 + k0 + skp);
            *(ushort8*)&Ash[0][row * 32 + skp] = va_h;
            *(ushort8*)&Ash[1][row * 32 + skp] = va_l;
        }
        {
            int gnB = tn + srow;
            ushort8 vb_h = *(const ushort8*)(Bh + (size_t)gnB * 768 + k0 + skp);
            ushort8 vb_l = *(const ushort8*)(Bl + (size_t)gnB * 768 + k0 + skp);
            *(ushort8*)&Bsh[0][srow * 32 + skp] = vb_h;
            *(ushort8*)&Bsh[1][srow * 32 + skp] = vb_l;
        }
        __syncthreads();

        const int fr = lane & 15;
        const int fk = (lane >> 4) * 8;
        bf16x8 ah[4], al[4], bh[2], bl[2];
        #pragma unroll
        for (int i = 0; i < 4; ++i) {
            ah[i] = *(const bf16x8*)&Ash[0][(wm + i * 16 + fr) * 32 + fk];
            al[i] = *(const bf16x8*)&Ash[1][(wm + i * 16 + fr) * 32 + fk];
        }
        #pragma unroll
        for (int i = 0; i < 2; ++i) {
            bh[i] = *(const bf16x8*)&Bsh[0][(wn + i * 16 + fr) * 32 + fk];
            bl[i] = *(const bf16x8*)&Bsh[1][(wn + i * 16 + fr) * 32 + fk];
        }
        #pragma unroll
        for (int mi = 0; mi < 4; ++mi)
            #pragma unroll
            for (int ni = 0; ni < 2; ++ni) {
                acc[mi][ni] = __builtin_amdgcn_mfma_f32_16x16x32_bf16(ah[mi], bh[ni], acc[mi][ni], 0, 0, 0);
                acc[mi][ni] = __builtin_amdgcn_mfma_f32_16x16x32_bf16(ah[mi], bl[ni], acc[mi][ni], 0, 0, 0);
                acc[mi][ni] = __builtin_amdgcn_mfma_f32_16x16x32_bf16(al[mi], bh[ni], acc[mi][ni], 0, 0, 0);
            }
        __syncthreads();
    }

    const int fr = lane & 15;
    const int fq = (lane >> 4) * 4;
    #pragma unroll
    for (int mi = 0; mi < 4; ++mi) {
        #pragma unroll
        for (int ni = 0; ni < 2; ++ni) {
            int n = tn + wn + ni * 16 + fr;
            float bb = bias[n];
            #pragma unroll
            for (int r = 0; r < 4; ++r) {
                int m = tm + wm + mi * 16 + fq + r;
                if (m >= M) continue;
                float val = acc[mi][ni][r] + bb;
                if (MODE == 0) {
                    out0[(size_t)m * N + n] = val;
                } else {
                    int which = n / C_;
                    int rr = n - which * C_;
                    int h = rr >> 6, d = rr & 63;
                    float* dst = (which == 0) ? out0 : (which == 1) ? out1 : out2;
                    HL hl2 = split2(val);
                    ((unsigned int*)dst)[((size_t)h * N_ + m) * D_ + d] =
                        ((unsigned int)hl2.h << 16) | hl2.l;
                }
            }
        }
    }
}

// ---------------------------------------------------------------------------
// Spatial attention, split-K flash decode (unchanged).
// ---------------------------------------------------------------------------
__global__ __launch_bounds__(256)
void attn_spatial_part(const unsigned int* __restrict__ qp, const unsigned int* __restrict__ kp,
                       const unsigned int* __restrict__ vp, float* __restrict__ part)
{
    const int sp = blockIdx.x;
    const int h  = blockIdx.y;
    const int tid = threadIdx.x;
    const int n0 = sp * 64;

    __shared__ float qs[NS_][65];
    __shared__ float ks[64][65];
    __shared__ float vs[64][65];
    __shared__ float ps[NS_][65];
    __shared__ float red_m[NS_], red_l[NS_];

    for (int i = tid; i < NS_ * 64; i += 256) {
        int r = i >> 6, d = i & 63;
        qs[r][d] = unpk(qp[(((size_t)h * N_ + r) << 6) + d]);
    }
    for (int i = tid; i < 64 * 16; i += 256) {
        int j = i >> 4, dq = (i & 15) << 2;
        int n = n0 + j; if (n >= N_) n = N_ - 1;
        uint4v kv = *(const uint4v*)(kp + (((size_t)h * N_ + n) << 6) + dq);
        uint4v vv = *(const uint4v*)(vp + (((size_t)h * N_ + n) << 6) + dq);
        ks[j][dq + 0] = unpk(kv.x); ks[j][dq + 1] = unpk(kv.y);
        ks[j][dq + 2] = unpk(kv.z); ks[j][dq + 3] = unpk(kv.w);
        vs[j][dq + 0] = unpk(vv.x); vs[j][dq + 1] = unpk(vv.y);
        vs[j][dq + 2] = unpk(vv.z); vs[j][dq + 3] = unpk(vv.w);
    }
    __syncthreads();

    const int j = tid & 63;
    const int rg = tid >> 6;
    const bool jvalid = (n0 + j) < N_;

    float sv[5];
    #pragma unroll
    for (int rr = 0; rr < 5; ++rr) {
        int r = rg * 5 + rr;
        float dot = 0.f;
        #pragma unroll 8
        for (int d = 0; d < 64; ++d) dot = fmaf(ks[j][d], qs[r][d], dot);
        sv[rr] = jvalid ? dot * 0.125f : -INFINITY;
    }
    #pragma unroll
    for (int rr = 0; rr < 5; ++rr) {
        int r = rg * 5 + rr;
        float mm = sv[rr];
        #pragma unroll
        for (int off = 1; off < 64; off <<= 1) mm = fmaxf(mm, __shfl_xor(mm, off, 64));
        float p = __expf(sv[rr] - mm);
        ps[r][j] = p;
        float ls = p;
        #pragma unroll
        for (int off = 1; off < 64; off <<= 1) ls += __shfl_xor(ls, off, 64);
        if (j == 0) { red_m[r] = mm; red_l[r] = ls; }
    }
    __syncthreads();

    const int d = tid & 63;
    float* po = part + ((size_t)(h * SPL + sp)) * (NS_ * 64);
    #pragma unroll
    for (int rr = 0; rr < 5; ++rr) {
        int r = rg * 5 + rr;
        float acc = 0.f;
        #pragma unroll 8
        for (int jj = 0; jj < 64; ++jj) acc = fmaf(ps[r][jj], vs[jj][d], acc);
        po[r * 64 + d] = acc;
    }
    if (tid < NS_) {
        float* pm = part + (size_t)H_ * SPL * NS_ * 64;
        float* pl = pm + (size_t)H_ * SPL * NS_;
        pm[(h * SPL + sp) * NS_ + tid] = red_m[tid];
        pl[(h * SPL + sp) * NS_ + tid] = red_l[tid];
    }
}

__global__ __launch_bounds__(64)
void attn_spatial_comb(const float* __restrict__ part,
                       unsigned short* __restrict__ atthi, unsigned short* __restrict__ attlo)
{
    const int s = blockIdx.x, h = blockIdx.y;
    const int d = threadIdx.x;
    const float* pm = part + (size_t)H_ * SPL * NS_ * 64;
    const float* pl = pm + (size_t)H_ * SPL * NS_;

    float M = -INFINITY;
    #pragma unroll 2
    for (int sp = 0; sp < SPL; ++sp)
        M = fmaxf(M, pm[(h * SPL + sp) * NS_ + s]);
    float num = 0.f, den = 0.f;
    for (int sp = 0; sp < SPL; ++sp) {
        float w = __expf(pm[(h * SPL + sp) * NS_ + s] - M);
        den = fmaf(pl[(h * SPL + sp) * NS_ + s], w, den);
        num = fmaf(part[((size_t)(h * SPL + sp)) * (NS_ * 64) + s * 64 + d], w, num);
    }
    HL hl = split2(num / den);
    size_t idx = (size_t)s * C_ + h * 64 + d;
    atthi[idx] = hl.h;
    attlo[idx] = hl.l;
}

// ---------------------------------------------------------------------------
// Pano attention, MFMA flash, SPLIT-K over chunks.
// 672 blocks (XCD-swizzled): tile (h,vw,pt) x half. half0: chunks 0-4 (dense),
// half1: chunks 5-8 (dense tail + cross window). Partials: packed o, m, l.
// ---------------------------------------------------------------------------
__global__ __launch_bounds__(256)
void attn_pano4(const unsigned int* __restrict__ qp, const unsigned int* __restrict__ kp,
                const unsigned int* __restrict__ vp,
                unsigned int* __restrict__ po, float* __restrict__ pm, float* __restrict__ pl)
{
    const int wg = xcd_swz(blockIdx.x, 672);
    const int half = wg & 1;
    const int t = wg >> 1;               // 0..335
    const int pt = t % PTILES;
    const int t2 = t / PTILES;
    const int vw = t2 & 3;
    const int h  = t2 >> 2;

    const int tid = threadIdx.x;
    const int lane = tid & 63;
    const int w = tid >> 6;
    const int p0 = pt * TPP;
    const int wr = w * 16;
    const int cv = (vw + 1) & 3;
    const int c = lane & 15;
    const int g = lane >> 4;

    __shared__ unsigned int Kl[64][68];
    __shared__ unsigned int VT[64][68];

    bf16x8 qh[2], ql[2];
    {
        int row = NS_ + vw * P_ + p0 + wr + c;
        if (row > N_ - 1) row = N_ - 1;
        const unsigned int* qrow = qp + (((size_t)h * N_ + row) << 6);
        #pragma unroll
        for (int ss = 0; ss < 2; ++ss) {
            uint4v u0 = *(const uint4v*)(qrow + ss * 32 + g * 8);
            uint4v u1 = *(const uint4v*)(qrow + ss * 32 + g * 8 + 4);
            unpack8(u0, u1, qh[ss], ql[ss]);
        }
    }

    float m[4], l[4];
    f32x4 o[4] = {};
    #pragma unroll
    for (int r = 0; r < 4; ++r) { m[r] = -INFINITY; l[r] = 0.f; }

    const int ch_lo = half ? 5 : 0;
    const int ch_hi = half ? 9 : 5;

    for (int ch = ch_lo; ch < ch_hi; ++ch) {
        #pragma unroll
        for (int i = 0; i < 4; ++i) {
            int f = i * 256 + tid;
            int key = f >> 4, dq = (f & 15) << 2;
            int n;
            if (ch < 7) {
                int sj = ch * 64 + key;
                n = (sj < NS_) ? sj : (NS_ + vw * P_ + (sj - NS_));
                if (sj >= NS_ + P_) n = 0;
            } else {
                int pp = p0 + (ch - 7) * 64 + key;
                if (pp >= P_) pp -= P_;
                if (pp >= P_) pp -= P_;
                n = NS_ + cv * P_ + pp;
            }
            uint4v kv = *(const uint4v*)(kp + (((size_t)h * N_ + n) << 6) + dq);
            *(uint4v*)&Kl[key][dq ^ (8 * (key & 3))] = kv;
        }
        {
            int kg = (tid & 15) << 2;
            int dq = (tid >> 4) << 2;
            uint4v rr[4];
            #pragma unroll
            for (int tt = 0; tt < 4; ++tt) {
                int key = kg + tt;
                int n;
                if (ch < 7) {
                    int sj = ch * 64 + key;
                    n = (sj < NS_) ? sj : (NS_ + vw * P_ + (sj - NS_));
                    if (sj >= NS_ + P_) n = 0;
                } else {
                    int pp = p0 + (ch - 7) * 64 + key;
                    if (pp >= P_) pp -= P_;
                    if (pp >= P_) pp -= P_;
                    n = NS_ + cv * P_ + pp;
                }
                rr[tt] = *(const uint4v*)(vp + (((size_t)h * N_ + n) << 6) + dq);
            }
            #pragma unroll
            for (int j = 0; j < 4; ++j) {
                uint4v wv;
                wv.x = rr[0][j]; wv.y = rr[1][j]; wv.z = rr[2][j]; wv.w = rr[3][j];
                *(uint4v*)&VT[dq + j][kg ^ (8 * j)] = wv;
            }
        }
        __syncthreads();

        f32x4 s[4] = {};
        #pragma unroll
        for (int ss = 0; ss < 2; ++ss) {
            #pragma unroll
            for (int nf = 0; nf < 4; ++nf) {
                int key = nf * 16 + c;
                int db = (ss * 32 + g * 8) ^ (8 * (key & 3));
                uint4v u0 = *(const uint4v*)&Kl[key][db];
                uint4v u1 = *(const uint4v*)&Kl[key][db + 4];
                bf16x8 kh, klv;
                unpack8(u0, u1, kh, klv);
                s[nf] = __builtin_amdgcn_mfma_f32_16x16x32_bf16(qh[ss], kh,  s[nf], 0, 0, 0);
                s[nf] = __builtin_amdgcn_mfma_f32_16x16x32_bf16(qh[ss], klv, s[nf], 0, 0, 0);
                s[nf] = __builtin_amdgcn_mfma_f32_16x16x32_bf16(ql[ss], kh,  s[nf], 0, 0, 0);
            }
        }

        #pragma unroll
        for (int nf = 0; nf < 4; ++nf) {
            int col = nf * 16 + c;
            #pragma unroll
            for (int r = 0; r < 4; ++r) {
                int rowl = wr + g * 4 + r;
                bool valid;
                if (ch < 7) {
                    valid = (ch * 64 + col) < (NS_ + P_);
                } else {
                    int i = (ch - 7) * 64 + col;
                    valid = (i < 127) && ((unsigned)(i - rowl) < 64u);
                }
                s[nf][r] = valid ? s[nf][r] * 0.125f : -INFINITY;
            }
        }

        float fct[4];
        #pragma unroll
        for (int r = 0; r < 4; ++r) {
            float cm = fmaxf(fmaxf(s[0][r], s[1][r]), fmaxf(s[2][r], s[3][r]));
            cm = fmaxf(cm, __shfl_xor(cm, 1, 64));
            cm = fmaxf(cm, __shfl_xor(cm, 2, 64));
            cm = fmaxf(cm, __shfl_xor(cm, 4, 64));
            cm = fmaxf(cm, __shfl_xor(cm, 8, 64));
            float nm = fmaxf(m[r], cm);
            fct[r] = __expf(m[r] - nm);
            m[r] = nm;
        }

        __syncthreads();

        float ps[4] = {0.f, 0.f, 0.f, 0.f};
        #pragma unroll
        for (int nf = 0; nf < 4; ++nf) {
            #pragma unroll
            for (int r = 0; r < 4; ++r) {
                float p = __expf(s[nf][r] - m[r]);
                ps[r] += p;
                HL hl2 = split2(p);
                int rowl = wr + g * 4 + r;
                int col = (nf * 16 + c) ^ (8 * (rowl & 3));
                Kl[rowl][col] = ((unsigned int)hl2.h << 16) | hl2.l;
            }
        }
        #pragma unroll
        for (int r = 0; r < 4; ++r) {
            ps[r] += __shfl_xor(ps[r], 1, 64);
            ps[r] += __shfl_xor(ps[r], 2, 64);
            ps[r] += __shfl_xor(ps[r], 4, 64);
            ps[r] += __shfl_xor(ps[r], 8, 64);
            l[r] = l[r] * fct[r] + ps[r];
        }
        #pragma unroll
        for (int nf = 0; nf < 4; ++nf)
            #pragma unroll
            for (int r = 0; r < 4; ++r)
                o[nf][r] *= fct[r];

        bf16x8 pah[2], pal[2];
        {
            int prow = wr + c;
            int xw = 8 * (prow & 3);
            #pragma unroll
            for (int ss = 0; ss < 2; ++ss) {
                int kb = (ss * 32 + g * 8) ^ xw;
                uint4v u0 = *(const uint4v*)&Kl[prow][kb];
                uint4v u1 = *(const uint4v*)&Kl[prow][kb + 4];
                unpack8(u0, u1, pah[ss], pal[ss]);
            }
        }

        int xv = 8 * (c & 3);
        #pragma unroll
        for (int ss = 0; ss < 2; ++ss) {
            #pragma unroll
            for (int nf = 0; nf < 4; ++nf) {
                int d = nf * 16 + c;
                int kb = (ss * 32 + g * 8) ^ xv;
                uint4v u0 = *(const uint4v*)&VT[d][kb];
                uint4v u1 = *(const uint4v*)&VT[d][kb + 4];
                bf16x8 vh, vl;
                unpack8(u0, u1, vh, vl);
                o[nf] = __builtin_amdgcn_mfma_f32_16x16x32_bf16(pah[ss], vh, o[nf], 0, 0, 0);
                o[nf] = __builtin_amdgcn_mfma_f32_16x16x32_bf16(pah[ss], vl, o[nf], 0, 0, 0);
                o[nf] = __builtin_amdgcn_mfma_f32_16x16x32_bf16(pal[ss], vh, o[nf], 0, 0, 0);
            }
        }
        __syncthreads();
    }

    // ---- write partials (unnormalized o, m, l) ----
    unsigned int* pob = po + (size_t)wg * 4096;
    #pragma unroll
    for (int r = 0; r < 4; ++r) {
        int rowl = wr + g * 4 + r;
        #pragma unroll
        for (int nf = 0; nf < 4; ++nf) {
            HL hl2 = split2(o[nf][r]);
            pob[rowl * 64 + nf * 16 + c] = ((unsigned int)hl2.h << 16) | hl2.l;
        }
        if (c == 0) {
            pm[(size_t)wg * 64 + rowl] = m[r];
            pl[(size_t)wg * 64 + rowl] = l[r];
        }
    }
}

// Combine the two chunk-halves per row. grid (PTILES, V_, H_), 256 threads.
__global__ __launch_bounds__(256)
void attn_pano_comb(const unsigned int* __restrict__ po, const float* __restrict__ pm,
                    const float* __restrict__ pl,
                    unsigned short* __restrict__ atthi, unsigned short* __restrict__ attlo)
{
    const int pt = blockIdx.x, vw = blockIdx.y, h = blockIdx.z;
    const int tid = threadIdx.x;
    const int d = tid & 63;
    const int rg = tid >> 6;
    const int tb = (((h * 4 + vw) * PTILES) + pt) * 2;

    for (int i = 0; i < 16; ++i) {
        int row = rg * 16 + i;
        int prow = pt * 64 + row;
        if (prow >= P_) break;
        float m0 = pm[(size_t)tb * 64 + row],      l0 = pl[(size_t)tb * 64 + row];
        float m1 = pm[(size_t)(tb + 1) * 64 + row], l1 = pl[(size_t)(tb + 1) * 64 + row];
        float M = fmaxf(m0, m1);
        float w0 = __expf(m0 - M), w1 = __expf(m1 - M);
        float inv = 1.0f / (l0 * w0 + l1 * w1);
        float o0 = unpk(po[(size_t)tb * 4096 + row * 64 + d]);
        float o1 = unpk(po[(size_t)(tb + 1) * 4096 + row * 64 + d]);
        float oo = (o0 * w0 + o1 * w1) * inv;
        HL hl = split2(oo);
        size_t idx = ((size_t)(NS_ + vw * P_ + prow)) * C_ + h * 64 + d;
        atthi[idx] = hl.h;
        attlo[idx] = hl.l;
    }
}

// ---------------------------------------------------------------------------
extern "C" void kernel_launch(void* const* d_in, const int* in_sizes, int n_in,
                              void* d_out, int out_size, void* d_ws, size_t ws_size,
                              hipStream_t stream)
{
    const float* x       = (const float*)d_in[0];
    const float* qkv_w   = (const float*)d_in[1];
    const float* qkv_b   = (const float*)d_in[2];
    const float* proj_w  = (const float*)d_in[3];
    const float* proj_b  = (const float*)d_in[4];
    float* out = (float*)d_out;

    const size_t per = (size_t)H_ * N_ * D_;
    unsigned int* qp = (unsigned int*)d_ws;
    unsigned int* kp = qp + per;
    unsigned int* vp = kp + per;
    unsigned short* xhi  = (unsigned short*)(vp + per);
    unsigned short* xlo  = xhi + (size_t)N_ * C_;
    unsigned short* whi  = xlo + (size_t)N_ * C_;
    unsigned short* wlo  = whi + (size_t)3 * C_ * C_;
    unsigned short* pwhi = wlo + (size_t)3 * C_ * C_;
    unsigned short* pwlo = pwhi + (size_t)C_ * C_;
    unsigned short* atthi = pwlo + (size_t)C_ * C_;
    unsigned short* attlo = atthi + (size_t)N_ * C_;
    float* spart = (float*)(attlo + (size_t)N_ * C_);
    // spart: [H_][SPL][20][64] + m/l: 2*[H_][SPL][20]
    unsigned int* ppo = (unsigned int*)(spart + (size_t)H_ * SPL * NS_ * 64 + 2 * (size_t)H_ * SPL * NS_);
    float* ppm = (float*)(ppo + (size_t)672 * 4096);
    float* ppl = ppm + (size_t)672 * 64;

    // 0) split inputs to bf16 hi/lo (single kernel)
    {
        int total = N4_X + N4_W + N4_PW;
        split_all<<<(total + 255) / 256, 256, 0, stream>>>(x, qkv_w, proj_w,
                                                           xhi, xlo, whi, wlo, pwhi, pwlo);
    }

    // 1) QKV projection (MFMA), 128x64 tiles, XCD-swizzled
    gemm_mfma<1><<<13 * 36, 256, 0, stream>>>(xhi, xlo, whi, wlo, qkv_b, N_, 3 * C_,
                                              (float*)qp, (float*)kp, (float*)vp);

    // 2) spatial attention: split-K partials + combine
    attn_spatial_part<<<dim3(SPL, H_), 256, 0, stream>>>(qp, kp, vp, spart);
    attn_spatial_comb<<<dim3(NS_, H_), 64, 0, stream>>>(spart, atthi, attlo);

    // 3) panoramic attention: chunk-split partials + combine
    attn_pano4<<<672, 256, 0, stream>>>(qp, kp, vp, ppo, ppm, ppl);
    attn_pano_comb<<<dim3(PTILES, V_, H_), 256, 0, stream>>>(ppo, ppm, ppl, atthi, attlo);

    // 4) output projection (MFMA), 128x64 tiles
    gemm_mfma<0><<<13 * 12, 256, 0, stream>>>(atthi, attlo, pwhi, pwlo, proj_b, N_, C_, out, nullptr, nullptr);
}

// Round 10
// 115.562 us; speedup vs baseline: 7.0259x; 1.1789x over previous
//
#include <hip/hip_runtime.h>
#include <hip/hip_bf16.h>
#include <math.h>

#define H_  12
#define N_  1620
#define D_  64
#define C_  768
#define NS_ 20
#define V_  4
#define P_  400

#define TPP    64
#define PTILES 7    // ceil(400/64)
#define SPL    26   // spatial key splits of 64

typedef __bf16 bf16x8 __attribute__((ext_vector_type(8)));
typedef float f32x4 __attribute__((ext_vector_type(4)));
typedef unsigned short ushort8 __attribute__((ext_vector_type(8)));
typedef unsigned short ushort4v __attribute__((ext_vector_type(4)));
typedef unsigned int uint4v __attribute__((ext_vector_type(4)));

struct HL { unsigned short h, l; };

__device__ __forceinline__ unsigned short bf16_rne(float v) {
    unsigned int u = __builtin_bit_cast(unsigned int, v);
    return (unsigned short)((u + 0x7fffu + ((u >> 16) & 1u)) >> 16);
}
__device__ __forceinline__ HL split2(float v) {
    HL r;
    r.h = bf16_rne(v);
    float hf = __builtin_bit_cast(float, (unsigned int)r.h << 16);
    r.l = bf16_rne(v - hf);
    return r;
}
__device__ __forceinline__ float unpk(unsigned int u) {
    return __builtin_bit_cast(float, u & 0xffff0000u) + __builtin_bit_cast(float, u << 16);
}
__device__ __forceinline__ void unpack8(uint4v a, uint4v b, bf16x8& hi, bf16x8& lo) {
    ushort8 ea = __builtin_bit_cast(ushort8, a);
    ushort8 eb = __builtin_bit_cast(ushort8, b);
    hi = __builtin_bit_cast(bf16x8, __builtin_shufflevector(ea, eb, 1,3,5,7,9,11,13,15));
    lo = __builtin_bit_cast(bf16x8, __builtin_shufflevector(ea, eb, 0,2,4,6,8,10,12,14));
}
// bijective XCD-chunked swizzle (m204)
__device__ __forceinline__ int xcd_swz(int orig, int nwg) {
    int q = nwg >> 3, r = nwg & 7;
    int x = orig & 7, p = orig >> 3;
    return (x < r ? x * (q + 1) : r * (q + 1) + (x - r) * q) + p;
}
// async global->LDS, 16 bytes per lane; LDS dest = wave-uniform base + lane*16
__device__ __forceinline__ void gload16(const void* g, void* l) {
    __builtin_amdgcn_global_load_lds((const __attribute__((address_space(1))) void*)g,
                                     (__attribute__((address_space(3))) void*)l, 16, 0, 0);
}

// ---------------------------------------------------------------------------
#define N4_X  ((N_ * C_) / 4)
#define N4_W  ((3 * C_ * C_) / 4)
#define N4_PW ((C_ * C_) / 4)

__global__ __launch_bounds__(256)
void split_all(const float* __restrict__ x, const float* __restrict__ w,
               const float* __restrict__ pw,
               unsigned short* __restrict__ xhi, unsigned short* __restrict__ xlo,
               unsigned short* __restrict__ whi, unsigned short* __restrict__ wlo,
               unsigned short* __restrict__ pwhi, unsigned short* __restrict__ pwlo)
{
    int i = blockIdx.x * 256 + threadIdx.x;
    const float* src; unsigned short* dh; unsigned short* dl; int idx;
    if (i < N4_X)                { src = x;  dh = xhi;  dl = xlo;  idx = i; }
    else if (i < N4_X + N4_W)    { src = w;  dh = whi;  dl = wlo;  idx = i - N4_X; }
    else if (i < N4_X + N4_W + N4_PW) { src = pw; dh = pwhi; dl = pwlo; idx = i - N4_X - N4_W; }
    else return;
    float4 v = ((const float4*)src)[idx];
    HL a = split2(v.x), b = split2(v.y), c = split2(v.z), d = split2(v.w);
    ushort4v h, l;
    h.x = a.h; h.y = b.h; h.z = c.h; h.w = d.h;
    l.x = a.l; l.y = b.l; l.z = c.l; l.w = d.l;
    ((ushort4v*)dh)[idx] = h;
    ((ushort4v*)dl)[idx] = l;
}

// ---------------------------------------------------------------------------
// MFMA NT GEMM, split-2 bf16. Tile 128(M) x 64(N), BK=32, 4 waves (2x2).
// Staging via global_load_lds width=16 (LDS layout linear in tid).
// ---------------------------------------------------------------------------
template<int MODE>
__global__ __launch_bounds__(256)
void gemm_mfma(const unsigned short* __restrict__ Ah, const unsigned short* __restrict__ Al,
               const unsigned short* __restrict__ Bh, const unsigned short* __restrict__ Bl,
               const float* __restrict__ bias, int M, int N,
               float* __restrict__ out0, float* __restrict__ out1, float* __restrict__ out2)
{
    __shared__ unsigned short Ash[2][128 * 32];
    __shared__ unsigned short Bsh[2][64 * 32];
    const int tid = threadIdx.x;
    const int lane = tid & 63;
    const int w = tid >> 6;

    const int wg = xcd_swz(blockIdx.x, gridDim.x);
    const int tmc = (M + 127) >> 7;
    const int tm = (wg % tmc) * 128;
    const int tn = (wg / tmc) * 64;

    const int wm = (w >> 1) * 64;
    const int wn = (w & 1) * 32;

    f32x4 acc[4][2] = {};

    const int lrow = lane >> 2;        // 0..15 row within a 16-row stripe
    const int lcol = (lane & 3) * 8;   // k-element offset

    for (int k0 = 0; k0 < 768; k0 += 32) {
        // A: wave w stages stripes 2w, 2w+1 (rows 32w..32w+31) for hi and lo
        #pragma unroll
        for (int t = 0; t < 2; ++t) {
            int row = w * 32 + t * 16 + lrow;
            int gmA = tm + row; if (gmA > M - 1) gmA = M - 1;
            gload16(Ah + (size_t)gmA * 768 + k0 + lcol, &Ash[0][(w * 2 + t) * 512]);
            gload16(Al + (size_t)gmA * 768 + k0 + lcol, &Ash[1][(w * 2 + t) * 512]);
        }
        // B: wave w stages stripe w (rows 16w..16w+15)
        {
            int gnB = tn + w * 16 + lrow;
            gload16(Bh + (size_t)gnB * 768 + k0 + lcol, &Bsh[0][w * 512]);
            gload16(Bl + (size_t)gnB * 768 + k0 + lcol, &Bsh[1][w * 512]);
        }
        __syncthreads();

        const int fr = lane & 15;
        const int fk = (lane >> 4) * 8;
        bf16x8 ah[4], al[4], bh[2], bl[2];
        #pragma unroll
        for (int i = 0; i < 4; ++i) {
            ah[i] = *(const bf16x8*)&Ash[0][(wm + i * 16 + fr) * 32 + fk];
            al[i] = *(const bf16x8*)&Ash[1][(wm + i * 16 + fr) * 32 + fk];
        }
        #pragma unroll
        for (int i = 0; i < 2; ++i) {
            bh[i] = *(const bf16x8*)&Bsh[0][(wn + i * 16 + fr) * 32 + fk];
            bl[i] = *(const bf16x8*)&Bsh[1][(wn + i * 16 + fr) * 32 + fk];
        }
        #pragma unroll
        for (int mi = 0; mi < 4; ++mi)
            #pragma unroll
            for (int ni = 0; ni < 2; ++ni) {
                acc[mi][ni] = __builtin_amdgcn_mfma_f32_16x16x32_bf16(ah[mi], bh[ni], acc[mi][ni], 0, 0, 0);
                acc[mi][ni] = __builtin_amdgcn_mfma_f32_16x16x32_bf16(ah[mi], bl[ni], acc[mi][ni], 0, 0, 0);
                acc[mi][ni] = __builtin_amdgcn_mfma_f32_16x16x32_bf16(al[mi], bh[ni], acc[mi][ni], 0, 0, 0);
            }
        __syncthreads();
    }

    const int fr = lane & 15;
    const int fq = (lane >> 4) * 4;
    #pragma unroll
    for (int mi = 0; mi < 4; ++mi) {
        #pragma unroll
        for (int ni = 0; ni < 2; ++ni) {
            int n = tn + wn + ni * 16 + fr;
            float bb = bias[n];
            #pragma unroll
            for (int r = 0; r < 4; ++r) {
                int m = tm + wm + mi * 16 + fq + r;
                if (m >= M) continue;
                float val = acc[mi][ni][r] + bb;
                if (MODE == 0) {
                    out0[(size_t)m * N + n] = val;
                } else {
                    int which = n / C_;
                    int rr = n - which * C_;
                    int h = rr >> 6, d = rr & 63;
                    float* dst = (which == 0) ? out0 : (which == 1) ? out1 : out2;
                    HL hl2 = split2(val);
                    ((unsigned int*)dst)[((size_t)h * N_ + m) * D_ + d] =
                        ((unsigned int)hl2.h << 16) | hl2.l;
                }
            }
        }
    }
}

// ---------------------------------------------------------------------------
// Fused attention partials: blocks [0,672) = pano split-K (XCD swizzled),
// blocks [672,984) = spatial split-K. Shared smem union (43.84 KB).
// ---------------------------------------------------------------------------
__global__ __launch_bounds__(256)
void attn_fused(const unsigned int* __restrict__ qp, const unsigned int* __restrict__ kp,
                const unsigned int* __restrict__ vp,
                unsigned int* __restrict__ po, float* __restrict__ pm, float* __restrict__ pl,
                float* __restrict__ spart)
{
    __shared__ __align__(16) unsigned char smem[43840];
    const int tid = threadIdx.x;

    if (blockIdx.x < 672) {
        // ================= PANO =================
        unsigned int (*Kl)[68] = (unsigned int (*)[68])smem;
        unsigned int (*VT)[68] = (unsigned int (*)[68])(smem + 17408);

        const int wg = xcd_swz(blockIdx.x, 672);
        const int half = wg & 1;
        const int t = wg >> 1;
        const int pt = t % PTILES;
        const int t2 = t / PTILES;
        const int vw = t2 & 3;
        const int h  = t2 >> 2;

        const int lane = tid & 63;
        const int w = tid >> 6;
        const int p0 = pt * TPP;
        const int wr = w * 16;
        const int cv = (vw + 1) & 3;
        const int c = lane & 15;
        const int g = lane >> 4;

        bf16x8 qh[2], ql[2];
        {
            int row = NS_ + vw * P_ + p0 + wr + c;
            if (row > N_ - 1) row = N_ - 1;
            const unsigned int* qrow = qp + (((size_t)h * N_ + row) << 6);
            #pragma unroll
            for (int ss = 0; ss < 2; ++ss) {
                uint4v u0 = *(const uint4v*)(qrow + ss * 32 + g * 8);
                uint4v u1 = *(const uint4v*)(qrow + ss * 32 + g * 8 + 4);
                unpack8(u0, u1, qh[ss], ql[ss]);
            }
        }

        float m[4], l[4];
        f32x4 o[4] = {};
        #pragma unroll
        for (int r = 0; r < 4; ++r) { m[r] = -INFINITY; l[r] = 0.f; }

        const int ch_lo = half ? 5 : 0;
        const int ch_hi = half ? 9 : 5;

        for (int ch = ch_lo; ch < ch_hi; ++ch) {
            #pragma unroll
            for (int i = 0; i < 4; ++i) {
                int f = i * 256 + tid;
                int key = f >> 4, dq = (f & 15) << 2;
                int n;
                if (ch < 7) {
                    int sj = ch * 64 + key;
                    n = (sj < NS_) ? sj : (NS_ + vw * P_ + (sj - NS_));
                    if (sj >= NS_ + P_) n = 0;
                } else {
                    int pp = p0 + (ch - 7) * 64 + key;
                    if (pp >= P_) pp -= P_;
                    if (pp >= P_) pp -= P_;
                    n = NS_ + cv * P_ + pp;
                }
                uint4v kv = *(const uint4v*)(kp + (((size_t)h * N_ + n) << 6) + dq);
                *(uint4v*)&Kl[key][dq ^ (8 * (key & 3))] = kv;
            }
            {
                int kg = (tid & 15) << 2;
                int dq = (tid >> 4) << 2;
                uint4v rr[4];
                #pragma unroll
                for (int tt = 0; tt < 4; ++tt) {
                    int key = kg + tt;
                    int n;
                    if (ch < 7) {
                        int sj = ch * 64 + key;
                        n = (sj < NS_) ? sj : (NS_ + vw * P_ + (sj - NS_));
                        if (sj >= NS_ + P_) n = 0;
                    } else {
                        int pp = p0 + (ch - 7) * 64 + key;
                        if (pp >= P_) pp -= P_;
                        if (pp >= P_) pp -= P_;
                        n = NS_ + cv * P_ + pp;
                    }
                    rr[tt] = *(const uint4v*)(vp + (((size_t)h * N_ + n) << 6) + dq);
                }
                #pragma unroll
                for (int j = 0; j < 4; ++j) {
                    uint4v wv;
                    wv.x = rr[0][j]; wv.y = rr[1][j]; wv.z = rr[2][j]; wv.w = rr[3][j];
                    *(uint4v*)&VT[dq + j][kg ^ (8 * j)] = wv;
                }
            }
            __syncthreads();

            f32x4 s[4] = {};
            #pragma unroll
            for (int ss = 0; ss < 2; ++ss) {
                #pragma unroll
                for (int nf = 0; nf < 4; ++nf) {
                    int key = nf * 16 + c;
                    int db = (ss * 32 + g * 8) ^ (8 * (key & 3));
                    uint4v u0 = *(const uint4v*)&Kl[key][db];
                    uint4v u1 = *(const uint4v*)&Kl[key][db + 4];
                    bf16x8 kh, klv;
                    unpack8(u0, u1, kh, klv);
                    s[nf] = __builtin_amdgcn_mfma_f32_16x16x32_bf16(qh[ss], kh,  s[nf], 0, 0, 0);
                    s[nf] = __builtin_amdgcn_mfma_f32_16x16x32_bf16(qh[ss], klv, s[nf], 0, 0, 0);
                    s[nf] = __builtin_amdgcn_mfma_f32_16x16x32_bf16(ql[ss], kh,  s[nf], 0, 0, 0);
                }
            }

            #pragma unroll
            for (int nf = 0; nf < 4; ++nf) {
                int col = nf * 16 + c;
                #pragma unroll
                for (int r = 0; r < 4; ++r) {
                    int rowl = wr + g * 4 + r;
                    bool valid;
                    if (ch < 7) {
                        valid = (ch * 64 + col) < (NS_ + P_);
                    } else {
                        int i = (ch - 7) * 64 + col;
                        valid = (i < 127) && ((unsigned)(i - rowl) < 64u);
                    }
                    s[nf][r] = valid ? s[nf][r] * 0.125f : -INFINITY;
                }
            }

            float fct[4];
            #pragma unroll
            for (int r = 0; r < 4; ++r) {
                float cm = fmaxf(fmaxf(s[0][r], s[1][r]), fmaxf(s[2][r], s[3][r]));
                cm = fmaxf(cm, __shfl_xor(cm, 1, 64));
                cm = fmaxf(cm, __shfl_xor(cm, 2, 64));
                cm = fmaxf(cm, __shfl_xor(cm, 4, 64));
                cm = fmaxf(cm, __shfl_xor(cm, 8, 64));
                float nm = fmaxf(m[r], cm);
                fct[r] = __expf(m[r] - nm);
                m[r] = nm;
            }

            __syncthreads();

            float ps[4] = {0.f, 0.f, 0.f, 0.f};
            #pragma unroll
            for (int nf = 0; nf < 4; ++nf) {
                #pragma unroll
                for (int r = 0; r < 4; ++r) {
                    float p = __expf(s[nf][r] - m[r]);
                    ps[r] += p;
                    HL hl2 = split2(p);
                    int rowl = wr + g * 4 + r;
                    int col = (nf * 16 + c) ^ (8 * (rowl & 3));
                    Kl[rowl][col] = ((unsigned int)hl2.h << 16) | hl2.l;
                }
            }
            #pragma unroll
            for (int r = 0; r < 4; ++r) {
                ps[r] += __shfl_xor(ps[r], 1, 64);
                ps[r] += __shfl_xor(ps[r], 2, 64);
                ps[r] += __shfl_xor(ps[r], 4, 64);
                ps[r] += __shfl_xor(ps[r], 8, 64);
                l[r] = l[r] * fct[r] + ps[r];
            }
            #pragma unroll
            for (int nf = 0; nf < 4; ++nf)
                #pragma unroll
                for (int r = 0; r < 4; ++r)
                    o[nf][r] *= fct[r];

            bf16x8 pah[2], pal[2];
            {
                int prow = wr + c;
                int xw = 8 * (prow & 3);
                #pragma unroll
                for (int ss = 0; ss < 2; ++ss) {
                    int kb = (ss * 32 + g * 8) ^ xw;
                    uint4v u0 = *(const uint4v*)&Kl[prow][kb];
                    uint4v u1 = *(const uint4v*)&Kl[prow][kb + 4];
                    unpack8(u0, u1, pah[ss], pal[ss]);
                }
            }

            int xv = 8 * (c & 3);
            #pragma unroll
            for (int ss = 0; ss < 2; ++ss) {
                #pragma unroll
                for (int nf = 0; nf < 4; ++nf) {
                    int d = nf * 16 + c;
                    int kb = (ss * 32 + g * 8) ^ xv;
                    uint4v u0 = *(const uint4v*)&VT[d][kb];
                    uint4v u1 = *(const uint4v*)&VT[d][kb + 4];
                    bf16x8 vh, vl;
                    unpack8(u0, u1, vh, vl);
                    o[nf] = __builtin_amdgcn_mfma_f32_16x16x32_bf16(pah[ss], vh, o[nf], 0, 0, 0);
                    o[nf] = __builtin_amdgcn_mfma_f32_16x16x32_bf16(pah[ss], vl, o[nf], 0, 0, 0);
                    o[nf] = __builtin_amdgcn_mfma_f32_16x16x32_bf16(pal[ss], vh, o[nf], 0, 0, 0);
                }
            }
            __syncthreads();
        }

        unsigned int* pob = po + (size_t)wg * 4096;
        #pragma unroll
        for (int r = 0; r < 4; ++r) {
            int rowl = wr + g * 4 + r;
            #pragma unroll
            for (int nf = 0; nf < 4; ++nf) {
                HL hl2 = split2(o[nf][r]);
                pob[rowl * 64 + nf * 16 + c] = ((unsigned int)hl2.h << 16) | hl2.l;
            }
            if (c == 0) {
                pm[(size_t)wg * 64 + rowl] = m[r];
                pl[(size_t)wg * 64 + rowl] = l[r];
            }
        }
    } else {
        // ================= SPATIAL =================
        float (*qs)[65] = (float (*)[65])smem;                       // 20x65
        float (*ks)[65] = (float (*)[65])(smem + 5200);              // 64x65
        float (*vs)[65] = (float (*)[65])(smem + 21840);             // 64x65
        float (*ps)[65] = (float (*)[65])(smem + 38480);             // 20x65
        float* red_m = (float*)(smem + 43680);
        float* red_l = red_m + NS_;

        const int id = blockIdx.x - 672;
        const int sp = id % SPL;
        const int h  = id / SPL;
        const int n0 = sp * 64;

        for (int i = tid; i < NS_ * 64; i += 256) {
            int r = i >> 6, d = i & 63;
            qs[r][d] = unpk(qp[(((size_t)h * N_ + r) << 6) + d]);
        }
        for (int i = tid; i < 64 * 16; i += 256) {
            int j = i >> 4, dq = (i & 15) << 2;
            int n = n0 + j; if (n >= N_) n = N_ - 1;
            uint4v kv = *(const uint4v*)(kp + (((size_t)h * N_ + n) << 6) + dq);
            uint4v vv = *(const uint4v*)(vp + (((size_t)h * N_ + n) << 6) + dq);
            ks[j][dq + 0] = unpk(kv.x); ks[j][dq + 1] = unpk(kv.y);
            ks[j][dq + 2] = unpk(kv.z); ks[j][dq + 3] = unpk(kv.w);
            vs[j][dq + 0] = unpk(vv.x); vs[j][dq + 1] = unpk(vv.y);
            vs[j][dq + 2] = unpk(vv.z); vs[j][dq + 3] = unpk(vv.w);
        }
        __syncthreads();

        const int j = tid & 63;
        const int rg = tid >> 6;
        const bool jvalid = (n0 + j) < N_;

        float sv[5];
        #pragma unroll
        for (int rr = 0; rr < 5; ++rr) {
            int r = rg * 5 + rr;
            float dot = 0.f;
            #pragma unroll 8
            for (int d = 0; d < 64; ++d) dot = fmaf(ks[j][d], qs[r][d], dot);
            sv[rr] = jvalid ? dot * 0.125f : -INFINITY;
        }
        #pragma unroll
        for (int rr = 0; rr < 5; ++rr) {
            int r = rg * 5 + rr;
            float mm = sv[rr];
            #pragma unroll
            for (int off = 1; off < 64; off <<= 1) mm = fmaxf(mm, __shfl_xor(mm, off, 64));
            float p = __expf(sv[rr] - mm);
            ps[r][j] = p;
            float ls = p;
            #pragma unroll
            for (int off = 1; off < 64; off <<= 1) ls += __shfl_xor(ls, off, 64);
            if (j == 0) { red_m[r] = mm; red_l[r] = ls; }
        }
        __syncthreads();

        const int d = tid & 63;
        float* pod = spart + ((size_t)(h * SPL + sp)) * (NS_ * 64);
        #pragma unroll
        for (int rr = 0; rr < 5; ++rr) {
            int r = rg * 5 + rr;
            float acc = 0.f;
            #pragma unroll 8
            for (int jj = 0; jj < 64; ++jj) acc = fmaf(ps[r][jj], vs[jj][d], acc);
            pod[r * 64 + d] = acc;
        }
        if (tid < NS_) {
            float* pms = spart + (size_t)H_ * SPL * NS_ * 64;
            float* pls = pms + (size_t)H_ * SPL * NS_;
            pms[(h * SPL + sp) * NS_ + tid] = red_m[tid];
            pls[(h * SPL + sp) * NS_ + tid] = red_l[tid];
        }
    }
}

// ---------------------------------------------------------------------------
// Fused combine: blocks [0,336) pano (2 halves), [336,396) spatial (4 rows ea).
// ---------------------------------------------------------------------------
__global__ __launch_bounds__(256)
void attn_comb(const unsigned int* __restrict__ po, const float* __restrict__ pm,
               const float* __restrict__ pl, const float* __restrict__ spart,
               unsigned short* __restrict__ atthi, unsigned short* __restrict__ attlo)
{
    const int b = blockIdx.x;
    const int tid = threadIdx.x;
    if (b < 336) {
        const int pt = b % PTILES;
        const int t2 = b / PTILES;
        const int vw = t2 & 3;
        const int h  = t2 >> 2;
        const int d = tid & 63;
        const int rg = tid >> 6;
        const int tb = b * 2;

        for (int i = 0; i < 16; ++i) {
            int row = rg * 16 + i;
            int prow = pt * 64 + row;
            if (prow >= P_) break;
            float m0 = pm[(size_t)tb * 64 + row],       l0 = pl[(size_t)tb * 64 + row];
            float m1 = pm[(size_t)(tb + 1) * 64 + row], l1 = pl[(size_t)(tb + 1) * 64 + row];
            float M = fmaxf(m0, m1);
            float w0 = __expf(m0 - M), w1 = __expf(m1 - M);
            float inv = 1.0f / (l0 * w0 + l1 * w1);
            float o0 = unpk(po[(size_t)tb * 4096 + row * 64 + d]);
            float o1 = unpk(po[(size_t)(tb + 1) * 4096 + row * 64 + d]);
            float oo = (o0 * w0 + o1 * w1) * inv;
            HL hl = split2(oo);
            size_t idx = ((size_t)(NS_ + vw * P_ + prow)) * C_ + h * 64 + d;
            atthi[idx] = hl.h;
            attlo[idx] = hl.l;
        }
    } else {
        const int rid = (b - 336) * 4 + (tid >> 6);   // 0..239
        const int s = rid % NS_;
        const int h = rid / NS_;
        const int d = tid & 63;
        const float* pms = spart + (size_t)H_ * SPL * NS_ * 64;
        const float* pls = pms + (size_t)H_ * SPL * NS_;

        float M = -INFINITY;
        #pragma unroll 2
        for (int sp = 0; sp < SPL; ++sp)
            M = fmaxf(M, pms[(h * SPL + sp) * NS_ + s]);
        float num = 0.f, den = 0.f;
        for (int sp = 0; sp < SPL; ++sp) {
            float w = __expf(pms[(h * SPL + sp) * NS_ + s] - M);
            den = fmaf(pls[(h * SPL + sp) * NS_ + s], w, den);
            num = fmaf(spart[((size_t)(h * SPL + sp)) * (NS_ * 64) + s * 64 + d], w, num);
        }
        HL hl = split2(num / den);
        size_t idx = (size_t)s * C_ + h * 64 + d;
        atthi[idx] = hl.h;
        attlo[idx] = hl.l;
    }
}

// ---------------------------------------------------------------------------
extern "C" void kernel_launch(void* const* d_in, const int* in_sizes, int n_in,
                              void* d_out, int out_size, void* d_ws, size_t ws_size,
                              hipStream_t stream)
{
    const float* x       = (const float*)d_in[0];
    const float* qkv_w   = (const float*)d_in[1];
    const float* qkv_b   = (const float*)d_in[2];
    const float* proj_w  = (const float*)d_in[3];
    const float* proj_b  = (const float*)d_in[4];
    float* out = (float*)d_out;

    const size_t per = (size_t)H_ * N_ * D_;
    unsigned int* qp = (unsigned int*)d_ws;
    unsigned int* kp = qp + per;
    unsigned int* vp = kp + per;
    unsigned short* xhi  = (unsigned short*)(vp + per);
    unsigned short* xlo  = xhi + (size_t)N_ * C_;
    unsigned short* whi  = xlo + (size_t)N_ * C_;
    unsigned short* wlo  = whi + (size_t)3 * C_ * C_;
    unsigned short* pwhi = wlo + (size_t)3 * C_ * C_;
    unsigned short* pwlo = pwhi + (size_t)C_ * C_;
    unsigned short* atthi = pwlo + (size_t)C_ * C_;
    unsigned short* attlo = atthi + (size_t)N_ * C_;
    float* spart = (float*)(attlo + (size_t)N_ * C_);
    unsigned int* ppo = (unsigned int*)(spart + (size_t)H_ * SPL * NS_ * 64 + 2 * (size_t)H_ * SPL * NS_);
    float* ppm = (float*)(ppo + (size_t)672 * 4096);
    float* ppl = ppm + (size_t)672 * 64;

    // 0) split inputs to bf16 hi/lo
    {
        int total = N4_X + N4_W + N4_PW;
        split_all<<<(total + 255) / 256, 256, 0, stream>>>(x, qkv_w, proj_w,
                                                           xhi, xlo, whi, wlo, pwhi, pwlo);
    }

    // 1) QKV projection (MFMA, global_load_lds staging)
    gemm_mfma<1><<<13 * 36, 256, 0, stream>>>(xhi, xlo, whi, wlo, qkv_b, N_, 3 * C_,
                                              (float*)qp, (float*)kp, (float*)vp);

    // 2) fused attention partials (pano split-K + spatial split-K)
    attn_fused<<<984, 256, 0, stream>>>(qp, kp, vp, ppo, ppm, ppl, spart);

    // 3) fused combine
    attn_comb<<<396, 256, 0, stream>>>(ppo, ppm, ppl, spart, atthi, attlo);

    // 4) output projection (MFMA)
    gemm_mfma<0><<<13 * 12, 256, 0, stream>>>(atthi, attlo, pwhi, pwlo, proj_b, N_, C_, out, nullptr, nullptr);
}